// Round 4
// baseline (5185.417 us; speedup 1.0000x reference)
//
#include <hip/hip_runtime.h>
#include <hip/hip_bf16.h>

typedef __hip_bfloat16 hipbf16;

#define H 128
#define NLAYERS 4
#define LN_EPS 1e-5f
#define ET 64           // edges/nodes per MFMA tile
#define RPB 8           // rows per edge block

typedef __bf16 bf16x8 __attribute__((ext_vector_type(8)));
typedef unsigned short ushort8 __attribute__((ext_vector_type(8)));
typedef float floatx16 __attribute__((ext_vector_type(16)));

union frag_u { ushort8 u; bf16x8 b; };

__device__ __forceinline__ float silu(float x) { return x / (1.f + __expf(-x)); }
__device__ __forceinline__ float b2f_bits(unsigned short u) { return __uint_as_float(((unsigned)u) << 16); }
__device__ __forceinline__ unsigned short f2b(float f) {
    unsigned u = __float_as_uint(f);
    unsigned r = ((u >> 16) & 1u) + 0x7fffu;
    return (unsigned short)((u + r) >> 16);
}

// ---------------- dtype detection (wire fp32 vs bf16) ----------------
__global__ void detect_kernel(const unsigned short* __restrict__ p, int nHalf,
                              int* __restrict__ flag) {
    int t = threadIdx.x;
    int bad = 0;
    for (int i = t; i < nHalf; i += 64) {
        unsigned short u = p[i];
        int e = (u >> 7) & 0xFF;
        if (e >= 0x8E) bad = 1;
    }
    unsigned long long m = __ballot(bad != 0);
    if (t == 0) *flag = (m != 0ULL) ? 1 : 0;   // 1 => fp32 wire
}

__global__ void conv_kernel(const void* __restrict__ src, float* __restrict__ dst,
                            int n, const int* __restrict__ flag) {
    int i = blockIdx.x * blockDim.x + threadIdx.x;
    if (i >= n) return;
    if (*flag) dst[i] = ((const float*)src)[i];
    else       dst[i] = b2f_bits(((const unsigned short*)src)[i]);
}

// Pack W[K x 128] (fp32) into MFMA B-fragment order
__global__ void pack_kernel(const float* __restrict__ W, unsigned short* __restrict__ blob,
                            int ksteps) {
    int idx = blockIdx.x * 256 + threadIdx.x;
    if (idx >= ksteps * 2048) return;
    int j  = idx & 7;
    int L  = (idx >> 3) & 63;
    int nt = (idx >> 9) & 3;
    int ks = idx >> 11;
    int k = ks * 16 + (L >> 5) * 8 + j;
    int n = nt * 32 + (L & 31);
    blob[idx] = f2b(W[k * H + n]);
}

__global__ void embed_kernel(const int* __restrict__ z, const float* __restrict__ emb,
                             float* __restrict__ h, unsigned short* __restrict__ hb, int n) {
    int idx = blockIdx.x * blockDim.x + threadIdx.x;
    if (idx >= n * H) return;
    int i = idx >> 7, j = idx & 127;
    float v = emb[z[i] * H + j];
    h[idx] = v;
    hb[idx] = f2b(v);
}

// ---------------- CSR build (counting sort by destination row) ----------------
__global__ void hist_kernel(const int* __restrict__ row, int* __restrict__ cnt, int nE) {
    int i = blockIdx.x * blockDim.x + threadIdx.x;
    if (i < nE) atomicAdd(&cnt[row[i]], 1);
}

__global__ __launch_bounds__(1024) void scan_kernel(const int* __restrict__ cnt,
                                                    int* __restrict__ rptr,
                                                    int* __restrict__ cur, int nN) {
    __shared__ int wsum[17];
    __shared__ int s_carry;
    int t = threadIdx.x;
    if (t == 0) s_carry = 0;
    __syncthreads();
    for (int base = 0; base < nN; base += 1024) {
        int i = base + t;
        int v = (i < nN) ? cnt[i] : 0;
        int x = v;
        #pragma unroll
        for (int off = 1; off < 64; off <<= 1) {
            int y = __shfl_up(x, off);
            if ((t & 63) >= off) x += y;
        }
        if ((t & 63) == 63) wsum[t >> 6] = x;
        __syncthreads();
        if (t == 0) {
            int s = 0;
            #pragma unroll
            for (int w = 0; w < 16; ++w) { int tmp = wsum[w]; wsum[w] = s; s += tmp; }
            wsum[16] = s;
        }
        __syncthreads();
        int cin = s_carry;
        int excl = cin + wsum[t >> 6] + (x - v);
        if (i < nN) { rptr[i] = excl; cur[i] = excl; }
        __syncthreads();
        if (t == 0) s_carry = cin + wsum[16];
        __syncthreads();
    }
    if (t == 0) rptr[nN] = s_carry;
}

__global__ void scatter_kernel(const int* __restrict__ row, const int* __restrict__ col,
                               const float* __restrict__ pos,
                               int* __restrict__ cur, int* __restrict__ colsS,
                               float* __restrict__ d2S, int nE) {
    int e = blockIdx.x * blockDim.x + threadIdx.x;
    if (e >= nE) return;
    int r = row[e], c = col[e];
    int p = atomicAdd(&cur[r], 1);
    colsS[p] = c;
    float dx = pos[r * 3 + 0] - pos[c * 3 + 0];
    float dy = pos[r * 3 + 1] - pos[c * 3 + 1];
    float dz = pos[r * 3 + 2] - pos[c * 3 + 2];
    d2S[p] = dx * dx + dy * dy + dz * dz;
}

// ---------------- edge MLP via MFMA, CSR gather-side aggregation ----------------
// Block owns RPB=8 destination rows; loops over its sorted edge span in 64-edge
// MFMA chunks; accumulates silu(MLP(m)) into LDS per-row accumulator; writes agg once.
__global__ __launch_bounds__(256) void edge_csr(
    const unsigned short* __restrict__ hb,
    const int* __restrict__ colsS, const float* __restrict__ d2S,
    const int* __restrict__ rptr,
    const unsigned short* __restrict__ pb1, const float* __restrict__ b1,
    const float* __restrict__ w1last,
    const unsigned short* __restrict__ pb2, const float* __restrict__ b2,
    float* __restrict__ agg, int nN)
{
    __shared__ __align__(16) unsigned short sA[ET * 264];  // GEMM1 A; sT aliased on top
    __shared__ float sAgg[(RPB + 1) * 132];                // slot 8 = pad dummy
    __shared__ int   sRptr[RPB + 1];
    __shared__ int   sSlot[ET];
    __shared__ int   sCol[ET];
    __shared__ float sD2[ET];

    const int t = threadIdx.x;
    const int r0 = blockIdx.x * RPB;

    if (t < RPB + 1) sRptr[t] = rptr[min(r0 + t, nN)];
    for (int i = t; i < (RPB + 1) * 132; i += 256) sAgg[i] = 0.f;
    __syncthreads();

    const int begin = sRptr[0], end = sRptr[RPB];
    const int nChunk = (end - begin + ET - 1) >> 6;

    const int lane = t & 63;
    const int wv = t >> 6;
    const int wm = wv & 1, wn = wv >> 1;
    const int lm = lane & 31, lh = lane >> 5;
    const int n0 = wn * 64 + lm;

    const float bias10 = b1[n0], bias11 = b1[n0 + 32];
    const float wl0 = w1last[n0], wl1 = w1last[n0 + 32];
    const float bias20 = b2[n0], bias21 = b2[n0 + 32];

    for (int ch = 0; ch < nChunk; ++ch) {
        const int p0 = begin + ch * ET;
        if (t < ET) {
            int p = p0 + t;
            int slot = RPB, c = r0; float dd = 0.f;
            if (p < end) {
                int sl = 0;
                while (p >= sRptr[sl + 1]) ++sl;
                slot = sl; c = colsS[p]; dd = d2S[p];
            }
            sSlot[t] = slot; sCol[t] = c; sD2[t] = dd;
        }
        __syncthreads();

        // gather A = [h[row] | h[col]] in bf16
        for (int cc = t; cc < ET * 32; cc += 256) {
            int e = cc >> 5;
            int half = (cc >> 4) & 1;
            int sl = sSlot[e];
            int node = half ? sCol[e] : (sl < RPB ? r0 + sl : r0);
            ushort8 v = *(const ushort8*)(hb + (size_t)node * H + (cc & 15) * 8);
            *(ushort8*)(sA + e * 264 + (cc & 15) * 8 + half * 128) = v;
        }
        __syncthreads();

        // GEMM1: [64,256] @ [256,128]
        floatx16 acc0 = {}, acc1 = {};
        const unsigned short* A0 = sA + (wm * 32 + lm) * 264 + lh * 8;
        #pragma unroll
        for (int ks = 0; ks < 16; ++ks) {
            frag_u a, fb0, fb1;
            a.u   = *(const ushort8*)(A0 + ks * 16);
            fb0.u = *(const ushort8*)(pb1 + (size_t)((ks * 4 + wn * 2 + 0) * 64 + lane) * 8);
            fb1.u = *(const ushort8*)(pb1 + (size_t)((ks * 4 + wn * 2 + 1) * 64 + lane) * 8);
            acc0 = __builtin_amdgcn_mfma_f32_32x32x16_bf16(a.b, fb0.b, acc0, 0, 0, 0);
            acc1 = __builtin_amdgcn_mfma_f32_32x32x16_bf16(a.b, fb1.b, acc1, 0, 0, 0);
        }
        __syncthreads();   // all sA reads done before sT (aliased) is written

        unsigned short* sT = sA;    // [m][k<128], stride 136
        #pragma unroll
        for (int r = 0; r < 16; ++r) {
            int m = wm * 32 + (r & 3) + 8 * (r >> 2) + 4 * lh;
            float dd = sD2[m];
            sT[m * 136 + n0]      = f2b(silu(acc0[r] + bias10 + dd * wl0));
            sT[m * 136 + n0 + 32] = f2b(silu(acc1[r] + bias11 + dd * wl1));
        }
        __syncthreads();

        // GEMM2: [64,128] @ [128,128]
        floatx16 c0 = {}, c1 = {};
        const unsigned short* A2 = sT + (wm * 32 + lm) * 136 + lh * 8;
        #pragma unroll
        for (int ks = 0; ks < 8; ++ks) {
            frag_u a, fb0, fb1;
            a.u   = *(const ushort8*)(A2 + ks * 16);
            fb0.u = *(const ushort8*)(pb2 + (size_t)((ks * 4 + wn * 2 + 0) * 64 + lane) * 8);
            fb1.u = *(const ushort8*)(pb2 + (size_t)((ks * 4 + wn * 2 + 1) * 64 + lane) * 8);
            c0 = __builtin_amdgcn_mfma_f32_32x32x16_bf16(a.b, fb0.b, c0, 0, 0, 0);
            c1 = __builtin_amdgcn_mfma_f32_32x32x16_bf16(a.b, fb1.b, c1, 0, 0, 0);
        }
        #pragma unroll
        for (int r = 0; r < 16; ++r) {
            int m = wm * 32 + (r & 3) + 8 * (r >> 2) + 4 * lh;
            int sl = sSlot[m];
            atomicAdd(&sAgg[sl * 132 + n0],      silu(c0[r] + bias20));
            atomicAdd(&sAgg[sl * 132 + n0 + 32], silu(c1[r] + bias21));
        }
        __syncthreads();   // sT reads + sAgg adds done before next chunk overwrites
    }

    // non-atomic writeout: rows are block-exclusive
    for (int i = t; i < RPB * H; i += 256) {
        int rr = i >> 7, f = i & 127;
        int node = r0 + rr;
        if (node < nN) agg[(size_t)node * H + f] = sAgg[rr * 132 + f];
    }
}

// ---------------- node MLP via MFMA ----------------
__global__ __launch_bounds__(256) void node_mfma(
    const unsigned short* __restrict__ hb,
    const float* __restrict__ aggf,
    const unsigned short* __restrict__ pn1, const float* __restrict__ b1,
    const unsigned short* __restrict__ pn2, const float* __restrict__ b2,
    float* __restrict__ hnew, int nN)
{
    __shared__ __align__(16) unsigned short sA[ET * 264];
    __shared__ __align__(16) unsigned short sT[ET * 136];

    const int t = threadIdx.x;
    const int i0 = blockIdx.x * ET;

    #pragma unroll
    for (int c = t; c < ET * 32; c += 256) {
        int e = c >> 5;
        int node = i0 + e; if (node >= nN) node = nN - 1;
        int f0 = (c & 31) * 8;
        ushort8 v;
        if (f0 < H) {
            v = *(const ushort8*)(hb + (size_t)node * H + f0);
        } else {
            const float* src = aggf + (size_t)node * H + (f0 - H);
            #pragma unroll
            for (int j = 0; j < 8; ++j) v[j] = f2b(src[j]);
        }
        *(ushort8*)(sA + e * 264 + (c & 31) * 8) = v;
    }
    __syncthreads();

    const int lane = t & 63;
    const int wv = t >> 6;
    const int wm = wv & 1, wn = wv >> 1;
    const int lm = lane & 31, lh = lane >> 5;

    floatx16 acc0 = {}, acc1 = {};
    const unsigned short* A0 = sA + (wm * 32 + lm) * 264 + lh * 8;
    #pragma unroll
    for (int ks = 0; ks < 16; ++ks) {
        frag_u a, fb0, fb1;
        a.u   = *(const ushort8*)(A0 + ks * 16);
        fb0.u = *(const ushort8*)(pn1 + (size_t)((ks * 4 + wn * 2 + 0) * 64 + lane) * 8);
        fb1.u = *(const ushort8*)(pn1 + (size_t)((ks * 4 + wn * 2 + 1) * 64 + lane) * 8);
        acc0 = __builtin_amdgcn_mfma_f32_32x32x16_bf16(a.b, fb0.b, acc0, 0, 0, 0);
        acc1 = __builtin_amdgcn_mfma_f32_32x32x16_bf16(a.b, fb1.b, acc1, 0, 0, 0);
    }
    {
        int n0 = wn * 64 + lm;
        float bias0 = b1[n0], bias1 = b1[n0 + 32];
        #pragma unroll
        for (int r = 0; r < 16; ++r) {
            int m = wm * 32 + (r & 3) + 8 * (r >> 2) + 4 * lh;
            sT[m * 136 + n0]      = f2b(silu(acc0[r] + bias0));
            sT[m * 136 + n0 + 32] = f2b(silu(acc1[r] + bias1));
        }
    }
    __syncthreads();

    floatx16 c0 = {}, c1 = {};
    const unsigned short* A2 = sT + (wm * 32 + lm) * 136 + lh * 8;
    #pragma unroll
    for (int ks = 0; ks < 8; ++ks) {
        frag_u a, fb0, fb1;
        a.u   = *(const ushort8*)(A2 + ks * 16);
        fb0.u = *(const ushort8*)(pn2 + (size_t)((ks * 4 + wn * 2 + 0) * 64 + lane) * 8);
        fb1.u = *(const ushort8*)(pn2 + (size_t)((ks * 4 + wn * 2 + 1) * 64 + lane) * 8);
        c0 = __builtin_amdgcn_mfma_f32_32x32x16_bf16(a.b, fb0.b, c0, 0, 0, 0);
        c1 = __builtin_amdgcn_mfma_f32_32x32x16_bf16(a.b, fb1.b, c1, 0, 0, 0);
    }
    {
        int n0 = wn * 64 + lm;
        float bias0 = b2[n0], bias1 = b2[n0 + 32];
        #pragma unroll
        for (int r = 0; r < 16; ++r) {
            int m = wm * 32 + (r & 3) + 8 * (r >> 2) + 4 * lh;
            int node = i0 + m;
            if (node < nN) {
                float* dst = hnew + (size_t)node * H;
                dst[n0]      = c0[r] + bias0;
                dst[n0 + 32] = c1[r] + bias1;
            }
        }
    }
}

// residual + layernorm; writes fp32 h and bf16 mirror
__global__ __launch_bounds__(256) void ln_kernel(
    float* __restrict__ h, unsigned short* __restrict__ hb,
    const float* __restrict__ hnew,
    const float* __restrict__ G, const float* __restrict__ B, int nN)
{
    __shared__ float rs[4], rq[4];
    int t = threadIdx.x;
    int local = t >> 7, j = t & 127;
    int i = blockIdx.x * 2 + local;
    float v = 0.f;
    if (i < nN) v = h[(size_t)i * H + j] + hnew[(size_t)i * H + j];
    float s = v, q = v * v;
    #pragma unroll
    for (int off = 32; off > 0; off >>= 1) {
        s += __shfl_down(s, off);
        q += __shfl_down(q, off);
    }
    int w = t >> 6;
    if ((t & 63) == 0) { rs[w] = s; rq[w] = q; }
    __syncthreads();
    int w0 = local * 2;
    float S = rs[w0] + rs[w0 + 1], Q = rq[w0] + rq[w0 + 1];
    float mu = S * (1.f / H);
    float var = Q * (1.f / H) - mu * mu;
    float y = (v - mu) * rsqrtf(var + LN_EPS) * G[j] + B[j];
    if (i < nN) {
        h[(size_t)i * H + j] = y;
        hb[(size_t)i * H + j] = f2b(y);
    }
}

__global__ void cast_kernel(const float* __restrict__ h, void* __restrict__ out,
                            int n, const int* __restrict__ flag) {
    int idx = blockIdx.x * blockDim.x + threadIdx.x;
    if (idx >= n) return;
    if (*flag) ((float*)out)[idx] = h[idx];
    else       ((hipbf16*)out)[idx] = __float2bfloat16(h[idx]);
}

extern "C" void kernel_launch(void* const* d_in, const int* in_sizes, int n_in,
                              void* d_out, int out_size, void* d_ws, size_t ws_size,
                              hipStream_t stream)
{
    const int* z  = (const int*)d_in[0];
    const int* ei = (const int*)d_in[2];

    const int nN = in_sizes[0];
    const int nE = in_sizes[2] / 2;
    const int* row = ei;
    const int* col = ei + nE;

    // ---- workspace layout ----
    float* ws   = (float*)d_ws;
    int*   flag = (int*)ws;
    float* h    = ws + 64;
    unsigned short* hb = (unsigned short*)(h + (size_t)nN * H);
    float* agg  = (float*)(hb + (size_t)nN * H);
    float* conv = agg + (size_t)nN * H;

    const int n_pos = in_sizes[1];
    const int n_emb = in_sizes[3];
    const int n_ew1 = in_sizes[4], n_eb1 = in_sizes[5];
    const int n_ew2 = in_sizes[6], n_eb2 = in_sizes[7];
    const int n_nw1 = in_sizes[8], n_nb1 = in_sizes[9];
    const int n_nw2 = in_sizes[10], n_nb2 = in_sizes[11];
    const int n_lng = in_sizes[12], n_lnb = in_sizes[13];

    float* pos = conv;
    float* emb = pos + n_pos;
    float* ew1 = emb + n_emb;
    float* eb1 = ew1 + n_ew1;
    float* ew2 = eb1 + n_eb1;
    float* eb2 = ew2 + n_ew2;
    float* nw1 = eb2 + n_eb2;
    float* nb1 = nw1 + n_nw1;
    float* nw2 = nb1 + n_nb1;
    float* nb2 = nw2 + n_nw2;
    float* lng = nb2 + n_nb2;
    float* lnb = lng + n_lng;
    float* conv_end = lnb + n_lnb;

    unsigned short* pb1 = (unsigned short*)conv_end;          // 4 x 32768
    unsigned short* pb2 = pb1 + 4 * 32768;                    // 4 x 16384
    unsigned short* pn1 = pb2 + 4 * 16384;                    // 4 x 32768
    unsigned short* pn2 = pn1 + 4 * 32768;                    // 4 x 16384

    int* cnt   = (int*)(pn2 + 4 * 16384);
    int* rptr  = cnt + nN;
    int* cur   = rptr + nN + 1;
    int* colsS = cur + nN;
    float* d2S = (float*)(colsS + nE);

    detect_kernel<<<1, 64, 0, stream>>>((const unsigned short*)d_in[4], 4096, flag);

    struct { const void* src; float* dst; int n; } cv[12] = {
        {d_in[1],  pos, n_pos}, {d_in[3],  emb, n_emb},
        {d_in[4],  ew1, n_ew1}, {d_in[5],  eb1, n_eb1},
        {d_in[6],  ew2, n_ew2}, {d_in[7],  eb2, n_eb2},
        {d_in[8],  nw1, n_nw1}, {d_in[9],  nb1, n_nb1},
        {d_in[10], nw2, n_nw2}, {d_in[11], nb2, n_nb2},
        {d_in[12], lng, n_lng}, {d_in[13], lnb, n_lnb},
    };
    for (int i = 0; i < 12; ++i)
        conv_kernel<<<(cv[i].n + 255) / 256, 256, 0, stream>>>(cv[i].src, cv[i].dst, cv[i].n, flag);

    for (int l = 0; l < NLAYERS; ++l) {
        pack_kernel<<<128, 256, 0, stream>>>(ew1 + (size_t)l * 257 * H, pb1 + l * 32768, 16);
        pack_kernel<<<64,  256, 0, stream>>>(ew2 + (size_t)l * H * H,   pb2 + l * 16384, 8);
        pack_kernel<<<128, 256, 0, stream>>>(nw1 + (size_t)l * 2 * H * H, pn1 + l * 32768, 16);
        pack_kernel<<<64,  256, 0, stream>>>(nw2 + (size_t)l * H * H,   pn2 + l * 16384, 8);
    }

    // CSR build (counting sort by destination row)
    hipMemsetAsync(cnt, 0, (size_t)nN * sizeof(int), stream);
    hist_kernel<<<(nE + 255) / 256, 256, 0, stream>>>(row, cnt, nE);
    scan_kernel<<<1, 1024, 0, stream>>>(cnt, rptr, cur, nN);
    scatter_kernel<<<(nE + 255) / 256, 256, 0, stream>>>(row, col, pos, cur, colsS, d2S, nE);

    embed_kernel<<<(nN * H + 255) / 256, 256, 0, stream>>>(z, emb, h, hb, nN);

    const int nBlocksE = (nN + RPB - 1) / RPB;
    for (int l = 0; l < NLAYERS; ++l) {
        edge_csr<<<nBlocksE, 256, 0, stream>>>(
            hb, colsS, d2S, rptr,
            pb1 + l * 32768, eb1 + (size_t)l * H,
            ew1 + (size_t)l * 257 * H + 256 * H,
            pb2 + l * 16384, eb2 + (size_t)l * H,
            agg, nN);
        node_mfma<<<(nN + ET - 1) / ET, 256, 0, stream>>>(
            hb, agg,
            pn1 + l * 32768, nb1 + (size_t)l * H,
            pn2 + l * 16384, nb2 + (size_t)l * H,
            agg /* hnew, overwritten in place */, nN);
        ln_kernel<<<(nN + 1) / 2, 256, 0, stream>>>(
            h, hb, agg, lng + (size_t)l * H, lnb + (size_t)l * H, nN);
    }
    cast_kernel<<<(nN * H + 255) / 256, 256, 0, stream>>>(h, d_out, nN * H, flag);
}

// Round 5
// 3114.090 us; speedup vs baseline: 1.6651x; 1.6651x over previous
//
#include <hip/hip_runtime.h>
#include <hip/hip_bf16.h>

typedef __hip_bfloat16 hipbf16;

#define H 128
#define NLAYERS 4
#define LN_EPS 1e-5f
#define ET 64           // edges/nodes per MFMA tile

typedef __bf16 bf16x8 __attribute__((ext_vector_type(8)));
typedef unsigned short ushort8 __attribute__((ext_vector_type(8)));
typedef float floatx16 __attribute__((ext_vector_type(16)));

union frag_u { ushort8 u; bf16x8 b; };

__device__ __forceinline__ float silu(float x) { return x / (1.f + __expf(-x)); }
__device__ __forceinline__ float b2f_bits(unsigned short u) { return __uint_as_float(((unsigned)u) << 16); }
__device__ __forceinline__ unsigned short f2b(float f) {
    unsigned u = __float_as_uint(f);
    unsigned r = ((u >> 16) & 1u) + 0x7fffu;
    return (unsigned short)((u + r) >> 16);
}

// ---------------- dtype detection (wire fp32 vs bf16) ----------------
__global__ void detect_kernel(const unsigned short* __restrict__ p, int nHalf,
                              int* __restrict__ flag) {
    int t = threadIdx.x;
    int bad = 0;
    for (int i = t; i < nHalf; i += 64) {
        unsigned short u = p[i];
        int e = (u >> 7) & 0xFF;
        if (e >= 0x8E) bad = 1;
    }
    unsigned long long m = __ballot(bad != 0);
    if (t == 0) *flag = (m != 0ULL) ? 1 : 0;   // 1 => fp32 wire
}

__global__ void conv_kernel(const void* __restrict__ src, float* __restrict__ dst,
                            int n, const int* __restrict__ flag) {
    int i = blockIdx.x * blockDim.x + threadIdx.x;
    if (i >= n) return;
    if (*flag) dst[i] = ((const float*)src)[i];
    else       dst[i] = b2f_bits(((const unsigned short*)src)[i]);
}

// Pack W[K x 128] (fp32) into MFMA B-fragment order
__global__ void pack_kernel(const float* __restrict__ W, unsigned short* __restrict__ blob,
                            int ksteps) {
    int idx = blockIdx.x * 256 + threadIdx.x;
    if (idx >= ksteps * 2048) return;
    int j  = idx & 7;
    int L  = (idx >> 3) & 63;
    int nt = (idx >> 9) & 3;
    int ks = idx >> 11;
    int k = ks * 16 + (L >> 5) * 8 + j;
    int n = nt * 32 + (L & 31);
    blob[idx] = f2b(W[k * H + n]);
}

__global__ void embed_kernel(const int* __restrict__ z, const float* __restrict__ emb,
                             float* __restrict__ h, unsigned short* __restrict__ hb, int n) {
    int idx = blockIdx.x * blockDim.x + threadIdx.x;
    if (idx >= n * H) return;
    int i = idx >> 7, j = idx & 127;
    float v = emb[z[i] * H + j];
    h[idx] = v;
    hb[idx] = f2b(v);
}

// ---------------- CSR build (counting sort by destination row) ----------------
__global__ void hist_kernel(const int* __restrict__ row, int* __restrict__ cnt, int nE) {
    int i = blockIdx.x * blockDim.x + threadIdx.x;
    if (i < nE) atomicAdd(&cnt[row[i]], 1);
}

__global__ __launch_bounds__(1024) void scan_kernel(const int* __restrict__ cnt,
                                                    int* __restrict__ rptr,
                                                    int* __restrict__ cur, int nN) {
    __shared__ int wsum[17];
    __shared__ int s_carry;
    int t = threadIdx.x;
    if (t == 0) s_carry = 0;
    __syncthreads();
    for (int base = 0; base < nN; base += 1024) {
        int i = base + t;
        int v = (i < nN) ? cnt[i] : 0;
        int x = v;
        #pragma unroll
        for (int off = 1; off < 64; off <<= 1) {
            int y = __shfl_up(x, off);
            if ((t & 63) >= off) x += y;
        }
        if ((t & 63) == 63) wsum[t >> 6] = x;
        __syncthreads();
        if (t == 0) {
            int s = 0;
            #pragma unroll
            for (int w = 0; w < 16; ++w) { int tmp = wsum[w]; wsum[w] = s; s += tmp; }
            wsum[16] = s;
        }
        __syncthreads();
        int cin = s_carry;
        int excl = cin + wsum[t >> 6] + (x - v);
        if (i < nN) { rptr[i] = excl; cur[i] = excl; }
        __syncthreads();
        if (t == 0) s_carry = cin + wsum[16];
        __syncthreads();
    }
    if (t == 0) rptr[nN] = s_carry;
}

__global__ void scatter_kernel(const int* __restrict__ row, const int* __restrict__ col,
                               const float* __restrict__ pos,
                               int* __restrict__ cur,
                               int* __restrict__ rowsS, int* __restrict__ colsS,
                               float* __restrict__ d2S, int nE) {
    int e = blockIdx.x * blockDim.x + threadIdx.x;
    if (e >= nE) return;
    int r = row[e], c = col[e];
    int p = atomicAdd(&cur[r], 1);
    rowsS[p] = r;
    colsS[p] = c;
    float dx = pos[r * 3 + 0] - pos[c * 3 + 0];
    float dy = pos[r * 3 + 1] - pos[c * 3 + 1];
    float dz = pos[r * 3 + 2] - pos[c * 3 + 2];
    d2S[p] = dx * dx + dy * dy + dz * dz;
}

// ---------------- edge MLP via MFMA on row-sorted edges ----------------
// One 64-edge tile per block (12500 blocks). Edges sorted by destination row:
// epilogue pre-reduces per-run into LDS, then ONE global atomicAdd per run-start.
__global__ __launch_bounds__(256) void edge_sorted(
    const unsigned short* __restrict__ hb,
    const int* __restrict__ rowsS, const int* __restrict__ colsS,
    const float* __restrict__ d2S,
    const unsigned short* __restrict__ pb1, const float* __restrict__ b1,
    const float* __restrict__ w1last,
    const unsigned short* __restrict__ pb2, const float* __restrict__ b2,
    float* __restrict__ agg, int nE)
{
    // one aliased region: GEMM1-A (33792 B) / GEMM2-A sT (17408 B) / sAgg (33792 B)
    __shared__ __align__(16) unsigned char smem[ET * 264 * 2];
    unsigned short* sA = (unsigned short*)smem;   // [m][k<256], stride 264
    unsigned short* sT = (unsigned short*)smem;   // [m][k<128], stride 136
    float*          sAgg = (float*)smem;          // [64][132]
    __shared__ int   sRow[ET];
    __shared__ int   sCol[ET];
    __shared__ int   sRS[ET];     // run-start index for each edge slot
    __shared__ float sD2[ET];

    const int t = threadIdx.x;
    const int e0 = blockIdx.x * ET;

    if (t < ET) {
        int p = e0 + t;
        if (p < nE) { sRow[t] = rowsS[p]; sCol[t] = colsS[p]; sD2[t] = d2S[p]; }
        else        { sRow[t] = -1;       sCol[t] = 0;        sD2[t] = 0.f;    }
    }
    __syncthreads();
    if (t < ET) {
        int prev = (t > 0) ? sRow[t - 1] : -2;
        int v = (sRow[t] != prev) ? t : 0;
        #pragma unroll
        for (int off = 1; off < 64; off <<= 1) {
            int u = __shfl_up(v, off);
            if (t >= off) v = max(v, u);
        }
        sRS[t] = v;
    }
    __syncthreads();

    // gather A = [h[row] | h[col]] in bf16
    #pragma unroll
    for (int c = t; c < ET * 32; c += 256) {
        int e = c >> 5;
        int half = (c >> 4) & 1;
        int node = half ? sCol[e] : sRow[e];
        if (node < 0) node = 0;
        ushort8 v = *(const ushort8*)(hb + (size_t)node * H + (c & 15) * 8);
        *(ushort8*)(sA + e * 264 + (c & 15) * 8 + half * 128) = v;
    }
    __syncthreads();

    const int lane = t & 63;
    const int wv = t >> 6;
    const int wm = wv & 1, wn = wv >> 1;
    const int lm = lane & 31, lh = lane >> 5;
    const int n0 = wn * 64 + lm;

    const float bias10 = b1[n0], bias11 = b1[n0 + 32];
    const float wl0 = w1last[n0], wl1 = w1last[n0 + 32];
    const float bias20 = b2[n0], bias21 = b2[n0 + 32];

    // GEMM1: [64,256] @ [256,128]
    floatx16 acc0 = {}, acc1 = {};
    const unsigned short* A0 = sA + (wm * 32 + lm) * 264 + lh * 8;
    #pragma unroll
    for (int ks = 0; ks < 16; ++ks) {
        frag_u a, fb0, fb1;
        a.u   = *(const ushort8*)(A0 + ks * 16);
        fb0.u = *(const ushort8*)(pb1 + (size_t)((ks * 4 + wn * 2 + 0) * 64 + lane) * 8);
        fb1.u = *(const ushort8*)(pb1 + (size_t)((ks * 4 + wn * 2 + 1) * 64 + lane) * 8);
        acc0 = __builtin_amdgcn_mfma_f32_32x32x16_bf16(a.b, fb0.b, acc0, 0, 0, 0);
        acc1 = __builtin_amdgcn_mfma_f32_32x32x16_bf16(a.b, fb1.b, acc1, 0, 0, 0);
    }
    __syncthreads();   // all sA reads done before sT (aliased) is written

    #pragma unroll
    for (int r = 0; r < 16; ++r) {
        int m = wm * 32 + (r & 3) + 8 * (r >> 2) + 4 * lh;
        float dd = sD2[m];
        sT[m * 136 + n0]      = f2b(silu(acc0[r] + bias10 + dd * wl0));
        sT[m * 136 + n0 + 32] = f2b(silu(acc1[r] + bias11 + dd * wl1));
    }
    __syncthreads();

    // GEMM2: [64,128] @ [128,128]
    floatx16 c0 = {}, c1 = {};
    const unsigned short* A2 = sT + (wm * 32 + lm) * 136 + lh * 8;
    #pragma unroll
    for (int ks = 0; ks < 8; ++ks) {
        frag_u a, fb0, fb1;
        a.u   = *(const ushort8*)(A2 + ks * 16);
        fb0.u = *(const ushort8*)(pb2 + (size_t)((ks * 4 + wn * 2 + 0) * 64 + lane) * 8);
        fb1.u = *(const ushort8*)(pb2 + (size_t)((ks * 4 + wn * 2 + 1) * 64 + lane) * 8);
        c0 = __builtin_amdgcn_mfma_f32_32x32x16_bf16(a.b, fb0.b, c0, 0, 0, 0);
        c1 = __builtin_amdgcn_mfma_f32_32x32x16_bf16(a.b, fb1.b, c1, 0, 0, 0);
    }
    __syncthreads();   // sT reads done before sAgg (aliased) is written

    // zero the per-run LDS accumulator
    for (int i = t; i < ET * 132; i += 256) sAgg[i] = 0.f;
    __syncthreads();

    // pre-reduce into run-start slots (LDS atomics, <=2-way same-address)
    #pragma unroll
    for (int r = 0; r < 16; ++r) {
        int m = wm * 32 + (r & 3) + 8 * (r >> 2) + 4 * lh;
        int slot = sRS[m];
        atomicAdd(&sAgg[slot * 132 + n0],      silu(c0[r] + bias20));
        atomicAdd(&sAgg[slot * 132 + n0 + 32], silu(c1[r] + bias21));
    }
    __syncthreads();

    // one global atomicAdd per run-start per feature (~5 runs/tile)
    for (int i = t; i < ET * H; i += 256) {
        int e = i >> 7, f = i & 127;         // e is wave-uniform per iteration
        if (sRS[e] == e && sRow[e] >= 0) {
            atomicAdd(&agg[(size_t)sRow[e] * H + f], sAgg[e * 132 + f]);
        }
    }
}

// ---------------- node MLP via MFMA ----------------
__global__ __launch_bounds__(256) void node_mfma(
    const unsigned short* __restrict__ hb,
    const float* __restrict__ aggf,
    const unsigned short* __restrict__ pn1, const float* __restrict__ b1,
    const unsigned short* __restrict__ pn2, const float* __restrict__ b2,
    float* __restrict__ hnew, int nN)
{
    __shared__ __align__(16) unsigned short sA[ET * 264];
    __shared__ __align__(16) unsigned short sT[ET * 136];

    const int t = threadIdx.x;
    const int i0 = blockIdx.x * ET;

    #pragma unroll
    for (int c = t; c < ET * 32; c += 256) {
        int e = c >> 5;
        int node = i0 + e; if (node >= nN) node = nN - 1;
        int f0 = (c & 31) * 8;
        ushort8 v;
        if (f0 < H) {
            v = *(const ushort8*)(hb + (size_t)node * H + f0);
        } else {
            const float* src = aggf + (size_t)node * H + (f0 - H);
            #pragma unroll
            for (int j = 0; j < 8; ++j) v[j] = f2b(src[j]);
        }
        *(ushort8*)(sA + e * 264 + (c & 31) * 8) = v;
    }
    __syncthreads();

    const int lane = t & 63;
    const int wv = t >> 6;
    const int wm = wv & 1, wn = wv >> 1;
    const int lm = lane & 31, lh = lane >> 5;

    floatx16 acc0 = {}, acc1 = {};
    const unsigned short* A0 = sA + (wm * 32 + lm) * 264 + lh * 8;
    #pragma unroll
    for (int ks = 0; ks < 16; ++ks) {
        frag_u a, fb0, fb1;
        a.u   = *(const ushort8*)(A0 + ks * 16);
        fb0.u = *(const ushort8*)(pn1 + (size_t)((ks * 4 + wn * 2 + 0) * 64 + lane) * 8);
        fb1.u = *(const ushort8*)(pn1 + (size_t)((ks * 4 + wn * 2 + 1) * 64 + lane) * 8);
        acc0 = __builtin_amdgcn_mfma_f32_32x32x16_bf16(a.b, fb0.b, acc0, 0, 0, 0);
        acc1 = __builtin_amdgcn_mfma_f32_32x32x16_bf16(a.b, fb1.b, acc1, 0, 0, 0);
    }
    {
        int n0 = wn * 64 + lm;
        float bias0 = b1[n0], bias1 = b1[n0 + 32];
        #pragma unroll
        for (int r = 0; r < 16; ++r) {
            int m = wm * 32 + (r & 3) + 8 * (r >> 2) + 4 * lh;
            sT[m * 136 + n0]      = f2b(silu(acc0[r] + bias0));
            sT[m * 136 + n0 + 32] = f2b(silu(acc1[r] + bias1));
        }
    }
    __syncthreads();

    floatx16 c0 = {}, c1 = {};
    const unsigned short* A2 = sT + (wm * 32 + lm) * 136 + lh * 8;
    #pragma unroll
    for (int ks = 0; ks < 8; ++ks) {
        frag_u a, fb0, fb1;
        a.u   = *(const ushort8*)(A2 + ks * 16);
        fb0.u = *(const ushort8*)(pn2 + (size_t)((ks * 4 + wn * 2 + 0) * 64 + lane) * 8);
        fb1.u = *(const ushort8*)(pn2 + (size_t)((ks * 4 + wn * 2 + 1) * 64 + lane) * 8);
        c0 = __builtin_amdgcn_mfma_f32_32x32x16_bf16(a.b, fb0.b, c0, 0, 0, 0);
        c1 = __builtin_amdgcn_mfma_f32_32x32x16_bf16(a.b, fb1.b, c1, 0, 0, 0);
    }
    {
        int n0 = wn * 64 + lm;
        float bias0 = b2[n0], bias1 = b2[n0 + 32];
        #pragma unroll
        for (int r = 0; r < 16; ++r) {
            int m = wm * 32 + (r & 3) + 8 * (r >> 2) + 4 * lh;
            int node = i0 + m;
            if (node < nN) {
                float* dst = hnew + (size_t)node * H;
                dst[n0]      = c0[r] + bias0;
                dst[n0 + 32] = c1[r] + bias1;
            }
        }
    }
}

// residual + layernorm; writes fp32 h and bf16 mirror
__global__ __launch_bounds__(256) void ln_kernel(
    float* __restrict__ h, unsigned short* __restrict__ hb,
    const float* __restrict__ hnew,
    const float* __restrict__ G, const float* __restrict__ B, int nN)
{
    __shared__ float rs[4], rq[4];
    int t = threadIdx.x;
    int local = t >> 7, j = t & 127;
    int i = blockIdx.x * 2 + local;
    float v = 0.f;
    if (i < nN) v = h[(size_t)i * H + j] + hnew[(size_t)i * H + j];
    float s = v, q = v * v;
    #pragma unroll
    for (int off = 32; off > 0; off >>= 1) {
        s += __shfl_down(s, off);
        q += __shfl_down(q, off);
    }
    int w = t >> 6;
    if ((t & 63) == 0) { rs[w] = s; rq[w] = q; }
    __syncthreads();
    int w0 = local * 2;
    float S = rs[w0] + rs[w0 + 1], Q = rq[w0] + rq[w0 + 1];
    float mu = S * (1.f / H);
    float var = Q * (1.f / H) - mu * mu;
    float y = (v - mu) * rsqrtf(var + LN_EPS) * G[j] + B[j];
    if (i < nN) {
        h[(size_t)i * H + j] = y;
        hb[(size_t)i * H + j] = f2b(y);
    }
}

__global__ void cast_kernel(const float* __restrict__ h, void* __restrict__ out,
                            int n, const int* __restrict__ flag) {
    int idx = blockIdx.x * blockDim.x + threadIdx.x;
    if (idx >= n) return;
    if (*flag) ((float*)out)[idx] = h[idx];
    else       ((hipbf16*)out)[idx] = __float2bfloat16(h[idx]);
}

extern "C" void kernel_launch(void* const* d_in, const int* in_sizes, int n_in,
                              void* d_out, int out_size, void* d_ws, size_t ws_size,
                              hipStream_t stream)
{
    const int* z  = (const int*)d_in[0];
    const int* ei = (const int*)d_in[2];

    const int nN = in_sizes[0];
    const int nE = in_sizes[2] / 2;
    const int* row = ei;
    const int* col = ei + nE;

    // ---- workspace layout ----
    float* ws   = (float*)d_ws;
    int*   flag = (int*)ws;
    float* h    = ws + 64;
    unsigned short* hb = (unsigned short*)(h + (size_t)nN * H);
    float* agg  = (float*)(hb + (size_t)nN * H);
    float* conv = agg + (size_t)nN * H;

    const int n_pos = in_sizes[1];
    const int n_emb = in_sizes[3];
    const int n_ew1 = in_sizes[4], n_eb1 = in_sizes[5];
    const int n_ew2 = in_sizes[6], n_eb2 = in_sizes[7];
    const int n_nw1 = in_sizes[8], n_nb1 = in_sizes[9];
    const int n_nw2 = in_sizes[10], n_nb2 = in_sizes[11];
    const int n_lng = in_sizes[12], n_lnb = in_sizes[13];

    float* pos = conv;
    float* emb = pos + n_pos;
    float* ew1 = emb + n_emb;
    float* eb1 = ew1 + n_ew1;
    float* ew2 = eb1 + n_eb1;
    float* eb2 = ew2 + n_ew2;
    float* nw1 = eb2 + n_eb2;
    float* nb1 = nw1 + n_nw1;
    float* nw2 = nb1 + n_nb1;
    float* nb2 = nw2 + n_nw2;
    float* lng = nb2 + n_nb2;
    float* lnb = lng + n_lng;
    float* conv_end = lnb + n_lnb;

    unsigned short* pb1 = (unsigned short*)conv_end;          // 4 x 32768
    unsigned short* pb2 = pb1 + 4 * 32768;                    // 4 x 16384
    unsigned short* pn1 = pb2 + 4 * 16384;                    // 4 x 32768
    unsigned short* pn2 = pn1 + 4 * 32768;                    // 4 x 16384

    int* cnt   = (int*)(pn2 + 4 * 16384);
    int* rptr  = cnt + nN;
    int* cur   = rptr + nN + 1;
    int* rowsS = cur + nN;
    int* colsS = rowsS + nE;
    float* d2S = (float*)(colsS + nE);

    detect_kernel<<<1, 64, 0, stream>>>((const unsigned short*)d_in[4], 4096, flag);

    struct { const void* src; float* dst; int n; } cv[12] = {
        {d_in[1],  pos, n_pos}, {d_in[3],  emb, n_emb},
        {d_in[4],  ew1, n_ew1}, {d_in[5],  eb1, n_eb1},
        {d_in[6],  ew2, n_ew2}, {d_in[7],  eb2, n_eb2},
        {d_in[8],  nw1, n_nw1}, {d_in[9],  nb1, n_nb1},
        {d_in[10], nw2, n_nw2}, {d_in[11], nb2, n_nb2},
        {d_in[12], lng, n_lng}, {d_in[13], lnb, n_lnb},
    };
    for (int i = 0; i < 12; ++i)
        conv_kernel<<<(cv[i].n + 255) / 256, 256, 0, stream>>>(cv[i].src, cv[i].dst, cv[i].n, flag);

    for (int l = 0; l < NLAYERS; ++l) {
        pack_kernel<<<128, 256, 0, stream>>>(ew1 + (size_t)l * 257 * H, pb1 + l * 32768, 16);
        pack_kernel<<<64,  256, 0, stream>>>(ew2 + (size_t)l * H * H,   pb2 + l * 16384, 8);
        pack_kernel<<<128, 256, 0, stream>>>(nw1 + (size_t)l * 2 * H * H, pn1 + l * 32768, 16);
        pack_kernel<<<64,  256, 0, stream>>>(nw2 + (size_t)l * H * H,   pn2 + l * 16384, 8);
    }

    // CSR-order edges (counting sort by destination row)
    hipMemsetAsync(cnt, 0, (size_t)nN * sizeof(int), stream);
    hist_kernel<<<(nE + 255) / 256, 256, 0, stream>>>(row, cnt, nE);
    scan_kernel<<<1, 1024, 0, stream>>>(cnt, rptr, cur, nN);
    scatter_kernel<<<(nE + 255) / 256, 256, 0, stream>>>(row, col, pos, cur, rowsS, colsS, d2S, nE);

    embed_kernel<<<(nN * H + 255) / 256, 256, 0, stream>>>(z, emb, h, hb, nN);

    const int nTiles = (nE + ET - 1) / ET;
    for (int l = 0; l < NLAYERS; ++l) {
        hipMemsetAsync(agg, 0, (size_t)nN * H * sizeof(float), stream);
        edge_sorted<<<nTiles, 256, 0, stream>>>(
            hb, rowsS, colsS, d2S,
            pb1 + l * 32768, eb1 + (size_t)l * H,
            ew1 + (size_t)l * 257 * H + 256 * H,
            pb2 + l * 16384, eb2 + (size_t)l * H,
            agg, nE);
        node_mfma<<<(nN + ET - 1) / ET, 256, 0, stream>>>(
            hb, agg,
            pn1 + l * 32768, nb1 + (size_t)l * H,
            pn2 + l * 16384, nb2 + (size_t)l * H,
            agg /* hnew, overwritten in place */, nN);
        ln_kernel<<<(nN + 1) / 2, 256, 0, stream>>>(
            h, hb, agg, lng + (size_t)l * H, lnb + (size_t)l * H, nN);
    }
    cast_kernel<<<(nN * H + 255) / 256, 256, 0, stream>>>(h, d_out, nN * H, flag);
}

// Round 7
// 1663.449 us; speedup vs baseline: 3.1173x; 1.8721x over previous
//
#include <hip/hip_runtime.h>
#include <hip/hip_bf16.h>

typedef __hip_bfloat16 hipbf16;

#define H 128
#define NLAYERS 4
#define LN_EPS 1e-5f
#define ET 64           // edges/nodes per MFMA tile

typedef __bf16 bf16x8 __attribute__((ext_vector_type(8)));
typedef unsigned short ushort8 __attribute__((ext_vector_type(8)));
typedef float floatx16 __attribute__((ext_vector_type(16)));

union frag_u { ushort8 u; bf16x8 b; };

__device__ __forceinline__ float silu(float x) { return x / (1.f + __expf(-x)); }
__device__ __forceinline__ float b2f_bits(unsigned short u) { return __uint_as_float(((unsigned)u) << 16); }
__device__ __forceinline__ unsigned short f2b(float f) {
    unsigned u = __float_as_uint(f);
    unsigned r = ((u >> 16) & 1u) + 0x7fffu;
    return (unsigned short)((u + r) >> 16);
}

// ---------------- dtype detection (wire fp32 vs bf16) ----------------
__global__ void detect_kernel(const unsigned short* __restrict__ p, int nHalf,
                              int* __restrict__ flag) {
    int t = threadIdx.x;
    int bad = 0;
    for (int i = t; i < nHalf; i += 64) {
        unsigned short u = p[i];
        int e = (u >> 7) & 0xFF;
        if (e >= 0x8E) bad = 1;
    }
    unsigned long long m = __ballot(bad != 0);
    if (t == 0) *flag = (m != 0ULL) ? 1 : 0;   // 1 => fp32 wire
}

__global__ void conv_kernel(const void* __restrict__ src, float* __restrict__ dst,
                            int n, const int* __restrict__ flag) {
    int i = blockIdx.x * blockDim.x + threadIdx.x;
    if (i >= n) return;
    if (*flag) dst[i] = ((const float*)src)[i];
    else       dst[i] = b2f_bits(((const unsigned short*)src)[i]);
}

// Pack W[K x 128] (fp32) into MFMA B-fragment order
__global__ void pack_kernel(const float* __restrict__ W, unsigned short* __restrict__ blob,
                            int ksteps) {
    int idx = blockIdx.x * 256 + threadIdx.x;
    if (idx >= ksteps * 2048) return;
    int j  = idx & 7;
    int L  = (idx >> 3) & 63;
    int nt = (idx >> 9) & 3;
    int ks = idx >> 11;
    int k = ks * 16 + (L >> 5) * 8 + j;
    int n = nt * 32 + (L & 31);
    blob[idx] = f2b(W[k * H + n]);
}

__global__ void embed_kernel(const int* __restrict__ z, const float* __restrict__ emb,
                             float* __restrict__ h, unsigned short* __restrict__ hb, int n) {
    int idx = blockIdx.x * blockDim.x + threadIdx.x;
    if (idx >= n * H) return;
    int i = idx >> 7, j = idx & 127;
    float v = emb[z[i] * H + j];
    h[idx] = v;
    hb[idx] = f2b(v);
}

// ---------------- CSR build (counting sort by destination row) ----------------
__global__ void hist_kernel(const int* __restrict__ row, int* __restrict__ cnt, int nE) {
    int i = blockIdx.x * blockDim.x + threadIdx.x;
    if (i < nE) atomicAdd(&cnt[row[i]], 1);
}

__global__ __launch_bounds__(1024) void scan_kernel(const int* __restrict__ cnt,
                                                    int* __restrict__ rptr,
                                                    int* __restrict__ cur, int nN) {
    __shared__ int wsum[17];
    __shared__ int s_carry;
    int t = threadIdx.x;
    if (t == 0) s_carry = 0;
    __syncthreads();
    for (int base = 0; base < nN; base += 1024) {
        int i = base + t;
        int v = (i < nN) ? cnt[i] : 0;
        int x = v;
        #pragma unroll
        for (int off = 1; off < 64; off <<= 1) {
            int y = __shfl_up(x, off);
            if ((t & 63) >= off) x += y;
        }
        if ((t & 63) == 63) wsum[t >> 6] = x;
        __syncthreads();
        if (t == 0) {
            int s = 0;
            #pragma unroll
            for (int w = 0; w < 16; ++w) { int tmp = wsum[w]; wsum[w] = s; s += tmp; }
            wsum[16] = s;
        }
        __syncthreads();
        int cin = s_carry;
        int excl = cin + wsum[t >> 6] + (x - v);
        if (i < nN) { rptr[i] = excl; cur[i] = excl; }
        __syncthreads();
        if (t == 0) s_carry = cin + wsum[16];
        __syncthreads();
    }
    if (t == 0) rptr[nN] = s_carry;
}

__global__ void scatter_kernel(const int* __restrict__ row, const int* __restrict__ col,
                               const float* __restrict__ pos,
                               int* __restrict__ cur,
                               int* __restrict__ rowsS, int* __restrict__ colsS,
                               float* __restrict__ d2S, int nE) {
    int e = blockIdx.x * blockDim.x + threadIdx.x;
    if (e >= nE) return;
    int r = row[e], c = col[e];
    int p = atomicAdd(&cur[r], 1);
    rowsS[p] = r;
    colsS[p] = c;
    float dx = pos[r * 3 + 0] - pos[c * 3 + 0];
    float dy = pos[r * 3 + 1] - pos[c * 3 + 1];
    float dz = pos[r * 3 + 2] - pos[c * 3 + 2];
    d2S[p] = dx * dx + dy * dy + dz * dz;
}

// ---------------- edge MLP via MFMA on sorted edges --------------------------
// Round-3 proven structure (3 barriers, separate sT). Sorted edges let each
// lane merge its 4 consecutive edges' outputs in registers before atomicAdd.
__global__ __launch_bounds__(256) void edge_reg(
    const unsigned short* __restrict__ hb,
    const int* __restrict__ rowsS, const int* __restrict__ colsS,
    const float* __restrict__ d2S,
    const unsigned short* __restrict__ pb1, const float* __restrict__ b1,
    const float* __restrict__ w1last,
    const unsigned short* __restrict__ pb2, const float* __restrict__ b2,
    float* __restrict__ agg, int nE)
{
    __shared__ __align__(16) unsigned short sA[ET * 264];  // [m][k<256]
    __shared__ __align__(16) unsigned short sT[ET * 136];  // [m][k<128]
    __shared__ int   sRow[ET];
    __shared__ int   sCol[ET];
    __shared__ float sD2[ET];

    const int t = threadIdx.x;
    const int p0 = blockIdx.x * ET;

    if (t < ET) {
        int p = p0 + t;
        if (p < nE) { sRow[t] = rowsS[p]; sCol[t] = colsS[p]; sD2[t] = d2S[p]; }
        else        { sRow[t] = -1;       sCol[t] = 0;        sD2[t] = 0.f;    }
    }
    __syncthreads();

    // gather A = [h[row] | h[col]] in bf16 (row side: ~5 distinct nodes, L1-hot)
    #pragma unroll
    for (int c = t; c < ET * 32; c += 256) {
        int e = c >> 5;
        int half = (c >> 4) & 1;
        int node = half ? sCol[e] : sRow[e];
        if (node < 0) node = 0;
        ushort8 v = *(const ushort8*)(hb + (size_t)node * H + (c & 15) * 8);
        *(ushort8*)(sA + e * 264 + (c & 15) * 8 + half * 128) = v;
    }
    __syncthreads();

    const int lane = t & 63;
    const int wv = t >> 6;
    const int wm = wv & 1, wn = wv >> 1;
    const int lm = lane & 31, lh = lane >> 5;
    const int n0 = wn * 64 + lm;

    const float bias10 = b1[n0], bias11 = b1[n0 + 32];
    const float wl0 = w1last[n0], wl1 = w1last[n0 + 32];
    const float bias20 = b2[n0], bias21 = b2[n0 + 32];

    // GEMM1: [64,256] @ [256,128]
    floatx16 acc0 = {}, acc1 = {};
    const unsigned short* A0 = sA + (wm * 32 + lm) * 264 + lh * 8;
    #pragma unroll
    for (int ks = 0; ks < 16; ++ks) {
        frag_u a, fb0, fb1;
        a.u   = *(const ushort8*)(A0 + ks * 16);
        fb0.u = *(const ushort8*)(pb1 + (size_t)((ks * 4 + wn * 2 + 0) * 64 + lane) * 8);
        fb1.u = *(const ushort8*)(pb1 + (size_t)((ks * 4 + wn * 2 + 1) * 64 + lane) * 8);
        acc0 = __builtin_amdgcn_mfma_f32_32x32x16_bf16(a.b, fb0.b, acc0, 0, 0, 0);
        acc1 = __builtin_amdgcn_mfma_f32_32x32x16_bf16(a.b, fb1.b, acc1, 0, 0, 0);
    }

    // epilogue 1: bias + d2*W1last, silu -> sT
    #pragma unroll
    for (int r = 0; r < 16; ++r) {
        int m = wm * 32 + (r & 3) + 8 * (r >> 2) + 4 * lh;
        float dd = sD2[m];
        sT[m * 136 + n0]      = f2b(silu(acc0[r] + bias10 + dd * wl0));
        sT[m * 136 + n0 + 32] = f2b(silu(acc1[r] + bias11 + dd * wl1));
    }
    __syncthreads();

    // GEMM2: [64,128] @ [128,128]
    floatx16 c0 = {}, c1 = {};
    const unsigned short* A2 = sT + (wm * 32 + lm) * 136 + lh * 8;
    #pragma unroll
    for (int ks = 0; ks < 8; ++ks) {
        frag_u a, fb0, fb1;
        a.u   = *(const ushort8*)(A2 + ks * 16);
        fb0.u = *(const ushort8*)(pb2 + (size_t)((ks * 4 + wn * 2 + 0) * 64 + lane) * 8);
        fb1.u = *(const ushort8*)(pb2 + (size_t)((ks * 4 + wn * 2 + 1) * 64 + lane) * 8);
        c0 = __builtin_amdgcn_mfma_f32_32x32x16_bf16(a.b, fb0.b, c0, 0, 0, 0);
        c1 = __builtin_amdgcn_mfma_f32_32x32x16_bf16(a.b, fb1.b, c1, 0, 0, 0);
    }

    // epilogue 2: silu + register run-compaction over 4 consecutive sorted edges
    // lane's registers r=g*4+k map to rows m = wm*32 + 4*lh + 8*g + k (k=0..3)
    #pragma unroll
    for (int g = 0; g < 4; ++g) {
        const int m0 = wm * 32 + 4 * lh + 8 * g;
        int prow = sRow[m0];
        float s0 = silu(c0[g * 4] + bias20);
        float s1 = silu(c1[g * 4] + bias21);
        #pragma unroll
        for (int k = 1; k < 4; ++k) {
            int rw = sRow[m0 + k];
            float u0 = silu(c0[g * 4 + k] + bias20);
            float u1 = silu(c1[g * 4 + k] + bias21);
            if (rw == prow) {
                s0 += u0; s1 += u1;
            } else {
                if (prow >= 0) {
                    atomicAdd(&agg[(size_t)prow * H + n0],      s0);
                    atomicAdd(&agg[(size_t)prow * H + n0 + 32], s1);
                }
                prow = rw; s0 = u0; s1 = u1;
            }
        }
        if (prow >= 0) {
            atomicAdd(&agg[(size_t)prow * H + n0],      s0);
            atomicAdd(&agg[(size_t)prow * H + n0 + 32], s1);
        }
    }
}

// ---------------- node MLP via MFMA ----------------
__global__ __launch_bounds__(256) void node_mfma(
    const unsigned short* __restrict__ hb,
    const float* __restrict__ aggf,
    const unsigned short* __restrict__ pn1, const float* __restrict__ b1,
    const unsigned short* __restrict__ pn2, const float* __restrict__ b2,
    float* __restrict__ hnew, int nN)
{
    __shared__ __align__(16) unsigned short sA[ET * 264];
    __shared__ __align__(16) unsigned short sT[ET * 136];

    const int t = threadIdx.x;
    const int i0 = blockIdx.x * ET;

    #pragma unroll
    for (int c = t; c < ET * 32; c += 256) {
        int e = c >> 5;
        int node = i0 + e; if (node >= nN) node = nN - 1;
        int f0 = (c & 31) * 8;
        ushort8 v;
        if (f0 < H) {
            v = *(const ushort8*)(hb + (size_t)node * H + f0);
        } else {
            const float* src = aggf + (size_t)node * H + (f0 - H);
            #pragma unroll
            for (int j = 0; j < 8; ++j) v[j] = f2b(src[j]);
        }
        *(ushort8*)(sA + e * 264 + (c & 31) * 8) = v;
    }
    __syncthreads();

    const int lane = t & 63;
    const int wv = t >> 6;
    const int wm = wv & 1, wn = wv >> 1;
    const int lm = lane & 31, lh = lane >> 5;

    floatx16 acc0 = {}, acc1 = {};
    const unsigned short* A0 = sA + (wm * 32 + lm) * 264 + lh * 8;
    #pragma unroll
    for (int ks = 0; ks < 16; ++ks) {
        frag_u a, fb0, fb1;
        a.u   = *(const ushort8*)(A0 + ks * 16);
        fb0.u = *(const ushort8*)(pn1 + (size_t)((ks * 4 + wn * 2 + 0) * 64 + lane) * 8);
        fb1.u = *(const ushort8*)(pn1 + (size_t)((ks * 4 + wn * 2 + 1) * 64 + lane) * 8);
        acc0 = __builtin_amdgcn_mfma_f32_32x32x16_bf16(a.b, fb0.b, acc0, 0, 0, 0);
        acc1 = __builtin_amdgcn_mfma_f32_32x32x16_bf16(a.b, fb1.b, acc1, 0, 0, 0);
    }
    {
        int n0 = wn * 64 + lm;
        float bias0 = b1[n0], bias1 = b1[n0 + 32];
        #pragma unroll
        for (int r = 0; r < 16; ++r) {
            int m = wm * 32 + (r & 3) + 8 * (r >> 2) + 4 * lh;
            sT[m * 136 + n0]      = f2b(silu(acc0[r] + bias0));
            sT[m * 136 + n0 + 32] = f2b(silu(acc1[r] + bias1));
        }
    }
    __syncthreads();

    floatx16 c0 = {}, c1 = {};
    const unsigned short* A2 = sT + (wm * 32 + lm) * 136 + lh * 8;
    #pragma unroll
    for (int ks = 0; ks < 8; ++ks) {
        frag_u a, fb0, fb1;
        a.u   = *(const ushort8*)(A2 + ks * 16);
        fb0.u = *(const ushort8*)(pn2 + (size_t)((ks * 4 + wn * 2 + 0) * 64 + lane) * 8);
        fb1.u = *(const ushort8*)(pn2 + (size_t)((ks * 4 + wn * 2 + 1) * 64 + lane) * 8);
        c0 = __builtin_amdgcn_mfma_f32_32x32x16_bf16(a.b, fb0.b, c0, 0, 0, 0);
        c1 = __builtin_amdgcn_mfma_f32_32x32x16_bf16(a.b, fb1.b, c1, 0, 0, 0);
    }
    {
        int n0 = wn * 64 + lm;
        float bias0 = b2[n0], bias1 = b2[n0 + 32];
        #pragma unroll
        for (int r = 0; r < 16; ++r) {
            int m = wm * 32 + (r & 3) + 8 * (r >> 2) + 4 * lh;
            int node = i0 + m;
            if (node < nN) {
                float* dst = hnew + (size_t)node * H;
                dst[n0]      = c0[r] + bias0;
                dst[n0 + 32] = c1[r] + bias1;
            }
        }
    }
}

// residual + layernorm; writes fp32 h and bf16 mirror
__global__ __launch_bounds__(256) void ln_kernel(
    float* __restrict__ h, unsigned short* __restrict__ hb,
    const float* __restrict__ hnew,
    const float* __restrict__ G, const float* __restrict__ B, int nN)
{
    __shared__ float rs[4], rq[4];
    int t = threadIdx.x;
    int local = t >> 7, j = t & 127;
    int i = blockIdx.x * 2 + local;
    float v = 0.f;
    if (i < nN) v = h[(size_t)i * H + j] + hnew[(size_t)i * H + j];
    float s = v, q = v * v;
    #pragma unroll
    for (int off = 32; off > 0; off >>= 1) {
        s += __shfl_down(s, off);
        q += __shfl_down(q, off);
    }
    int w = t >> 6;
    if ((t & 63) == 0) { rs[w] = s; rq[w] = q; }
    __syncthreads();
    int w0 = local * 2;
    float S = rs[w0] + rs[w0 + 1], Q = rq[w0] + rq[w0 + 1];
    float mu = S * (1.f / H);
    float var = Q * (1.f / H) - mu * mu;
    float y = (v - mu) * rsqrtf(var + LN_EPS) * G[j] + B[j];
    if (i < nN) {
        h[(size_t)i * H + j] = y;
        hb[(size_t)i * H + j] = f2b(y);
    }
}

__global__ void cast_kernel(const float* __restrict__ h, void* __restrict__ out,
                            int n, const int* __restrict__ flag) {
    int idx = blockIdx.x * blockDim.x + threadIdx.x;
    if (idx >= n) return;
    if (*flag) ((float*)out)[idx] = h[idx];
    else       ((hipbf16*)out)[idx] = __float2bfloat16(h[idx]);
}

extern "C" void kernel_launch(void* const* d_in, const int* in_sizes, int n_in,
                              void* d_out, int out_size, void* d_ws, size_t ws_size,
                              hipStream_t stream)
{
    const int* z  = (const int*)d_in[0];
    const int* ei = (const int*)d_in[2];

    const int nN = in_sizes[0];
    const int nE = in_sizes[2] / 2;
    const int* row = ei;
    const int* col = ei + nE;

    // ---- workspace layout (~77 MB total, proven safe) ----
    float* ws   = (float*)d_ws;
    int*   flag = (int*)ws;
    float* h    = ws + 64;
    unsigned short* hb = (unsigned short*)(h + (size_t)nN * H);
    float* agg  = (float*)(hb + (size_t)nN * H);
    float* conv = agg + (size_t)nN * H;

    const int n_pos = in_sizes[1];
    const int n_emb = in_sizes[3];
    const int n_ew1 = in_sizes[4], n_eb1 = in_sizes[5];
    const int n_ew2 = in_sizes[6], n_eb2 = in_sizes[7];
    const int n_nw1 = in_sizes[8], n_nb1 = in_sizes[9];
    const int n_nw2 = in_sizes[10], n_nb2 = in_sizes[11];
    const int n_lng = in_sizes[12], n_lnb = in_sizes[13];

    float* pos = conv;
    float* emb = pos + n_pos;
    float* ew1 = emb + n_emb;
    float* eb1 = ew1 + n_ew1;
    float* ew2 = eb1 + n_eb1;
    float* eb2 = ew2 + n_ew2;
    float* nw1 = eb2 + n_eb2;
    float* nb1 = nw1 + n_nw1;
    float* nw2 = nb1 + n_nb1;
    float* nb2 = nw2 + n_nw2;
    float* lng = nb2 + n_nb2;
    float* lnb = lng + n_lng;
    float* conv_end = lnb + n_lnb;

    unsigned short* pb1 = (unsigned short*)conv_end;          // 4 x 32768
    unsigned short* pb2 = pb1 + 4 * 32768;                    // 4 x 16384
    unsigned short* pn1 = pb2 + 4 * 16384;                    // 4 x 32768
    unsigned short* pn2 = pn1 + 4 * 32768;                    // 4 x 16384

    int* cnt   = (int*)(pn2 + 4 * 16384);
    int* rptr  = cnt + nN;
    int* cur   = rptr + nN + 1;
    int* rowsS = cur + nN;
    int* colsS = rowsS + nE;
    float* d2S = (float*)(colsS + nE);

    detect_kernel<<<1, 64, 0, stream>>>((const unsigned short*)d_in[4], 4096, flag);

    struct { const void* src; float* dst; int n; } cv[12] = {
        {d_in[1],  pos, n_pos}, {d_in[3],  emb, n_emb},
        {d_in[4],  ew1, n_ew1}, {d_in[5],  eb1, n_eb1},
        {d_in[6],  ew2, n_ew2}, {d_in[7],  eb2, n_eb2},
        {d_in[8],  nw1, n_nw1}, {d_in[9],  nb1, n_nb1},
        {d_in[10], nw2, n_nw2}, {d_in[11], nb2, n_nb2},
        {d_in[12], lng, n_lng}, {d_in[13], lnb, n_lnb},
    };
    for (int i = 0; i < 12; ++i)
        conv_kernel<<<(cv[i].n + 255) / 256, 256, 0, stream>>>(cv[i].src, cv[i].dst, cv[i].n, flag);

    for (int l = 0; l < NLAYERS; ++l) {
        pack_kernel<<<128, 256, 0, stream>>>(ew1 + (size_t)l * 257 * H, pb1 + l * 32768, 16);
        pack_kernel<<<64,  256, 0, stream>>>(ew2 + (size_t)l * H * H,   pb2 + l * 16384, 8);
        pack_kernel<<<128, 256, 0, stream>>>(nw1 + (size_t)l * 2 * H * H, pn1 + l * 32768, 16);
        pack_kernel<<<64,  256, 0, stream>>>(nw2 + (size_t)l * H * H,   pn2 + l * 16384, 8);
    }

    // CSR-order edges (counting sort by destination row)
    hipMemsetAsync(cnt, 0, (size_t)nN * sizeof(int), stream);
    hist_kernel<<<(nE + 255) / 256, 256, 0, stream>>>(row, cnt, nE);
    scan_kernel<<<1, 1024, 0, stream>>>(cnt, rptr, cur, nN);
    scatter_kernel<<<(nE + 255) / 256, 256, 0, stream>>>(row, col, pos, cur, rowsS, colsS, d2S, nE);

    embed_kernel<<<(nN * H + 255) / 256, 256, 0, stream>>>(z, emb, h, hb, nN);

    const int nTiles = (nE + ET - 1) / ET;
    for (int l = 0; l < NLAYERS; ++l) {
        hipMemsetAsync(agg, 0, (size_t)nN * H * sizeof(float), stream);
        edge_reg<<<nTiles, 256, 0, stream>>>(
            hb, rowsS, colsS, d2S,
            pb1 + l * 32768, eb1 + (size_t)l * H,
            ew1 + (size_t)l * 257 * H + 256 * H,
            pb2 + l * 16384, eb2 + (size_t)l * H,
            agg, nE);
        node_mfma<<<(nN + ET - 1) / ET, 256, 0, stream>>>(
            hb, agg,
            pn1 + l * 32768, nb1 + (size_t)l * H,
            pn2 + l * 16384, nb2 + (size_t)l * H,
            agg /* hnew, overwritten in place */, nN);
        ln_kernel<<<(nN + 1) / 2, 256, 0, stream>>>(
            h, hb, agg, lng + (size_t)l * H, lnb + (size_t)l * H, nN);
    }
    cast_kernel<<<(nN * H + 255) / 256, 256, 0, stream>>>(h, d_out, nN * H, flag);
}

// Round 8
// 1611.094 us; speedup vs baseline: 3.2186x; 1.0325x over previous
//
#include <hip/hip_runtime.h>
#include <hip/hip_bf16.h>

typedef __hip_bfloat16 hipbf16;

#define H 128
#define NLAYERS 4
#define LN_EPS 1e-5f
#define ET 64           // edges/nodes per MFMA tile

typedef __bf16 bf16x8 __attribute__((ext_vector_type(8)));
typedef unsigned short ushort8 __attribute__((ext_vector_type(8)));
typedef float floatx16 __attribute__((ext_vector_type(16)));

union frag_u { ushort8 u; bf16x8 b; };

__device__ __forceinline__ float silu(float x) { return x / (1.f + __expf(-x)); }
__device__ __forceinline__ float b2f_bits(unsigned short u) { return __uint_as_float(((unsigned)u) << 16); }
__device__ __forceinline__ unsigned short f2b(float f) {
    unsigned u = __float_as_uint(f);
    unsigned r = ((u >> 16) & 1u) + 0x7fffu;
    return (unsigned short)((u + r) >> 16);
}

// ---------------- dtype detection (wire fp32 vs bf16) ----------------
__global__ void detect_kernel(const unsigned short* __restrict__ p, int nHalf,
                              int* __restrict__ flag) {
    int t = threadIdx.x;
    int bad = 0;
    for (int i = t; i < nHalf; i += 64) {
        unsigned short u = p[i];
        int e = (u >> 7) & 0xFF;
        if (e >= 0x8E) bad = 1;
    }
    unsigned long long m = __ballot(bad != 0);
    if (t == 0) *flag = (m != 0ULL) ? 1 : 0;   // 1 => fp32 wire
}

__global__ void conv_kernel(const void* __restrict__ src, float* __restrict__ dst,
                            int n, const int* __restrict__ flag) {
    int i = blockIdx.x * blockDim.x + threadIdx.x;
    if (i >= n) return;
    if (*flag) dst[i] = ((const float*)src)[i];
    else       dst[i] = b2f_bits(((const unsigned short*)src)[i]);
}

// Pack W[K x 128] (fp32) into MFMA B-fragment order
__global__ void pack_kernel(const float* __restrict__ W, unsigned short* __restrict__ blob,
                            int ksteps) {
    int idx = blockIdx.x * 256 + threadIdx.x;
    if (idx >= ksteps * 2048) return;
    int j  = idx & 7;
    int L  = (idx >> 3) & 63;
    int nt = (idx >> 9) & 3;
    int ks = idx >> 11;
    int k = ks * 16 + (L >> 5) * 8 + j;
    int n = nt * 32 + (L & 31);
    blob[idx] = f2b(W[k * H + n]);
}

__global__ void embed_kernel(const int* __restrict__ z, const float* __restrict__ emb,
                             float* __restrict__ h, unsigned short* __restrict__ hb, int n) {
    int idx = blockIdx.x * blockDim.x + threadIdx.x;
    if (idx >= n * H) return;
    int i = idx >> 7, j = idx & 127;
    float v = emb[z[i] * H + j];
    h[idx] = v;
    hb[idx] = f2b(v);
}

// ---------------- CSR build (counting sort by destination row) ----------------
__global__ void hist_kernel(const int* __restrict__ row, int* __restrict__ cnt, int nE) {
    int i = blockIdx.x * blockDim.x + threadIdx.x;
    if (i < nE) atomicAdd(&cnt[row[i]], 1);
}

__global__ __launch_bounds__(1024) void scan_kernel(const int* __restrict__ cnt,
                                                    int* __restrict__ rptr,
                                                    int* __restrict__ cur, int nN) {
    __shared__ int wsum[17];
    __shared__ int s_carry;
    int t = threadIdx.x;
    if (t == 0) s_carry = 0;
    __syncthreads();
    for (int base = 0; base < nN; base += 1024) {
        int i = base + t;
        int v = (i < nN) ? cnt[i] : 0;
        int x = v;
        #pragma unroll
        for (int off = 1; off < 64; off <<= 1) {
            int y = __shfl_up(x, off);
            if ((t & 63) >= off) x += y;
        }
        if ((t & 63) == 63) wsum[t >> 6] = x;
        __syncthreads();
        if (t == 0) {
            int s = 0;
            #pragma unroll
            for (int w = 0; w < 16; ++w) { int tmp = wsum[w]; wsum[w] = s; s += tmp; }
            wsum[16] = s;
        }
        __syncthreads();
        int cin = s_carry;
        int excl = cin + wsum[t >> 6] + (x - v);
        if (i < nN) { rptr[i] = excl; cur[i] = excl; }
        __syncthreads();
        if (t == 0) s_carry = cin + wsum[16];
        __syncthreads();
    }
    if (t == 0) rptr[nN] = s_carry;
}

__global__ void scatter_kernel(const int* __restrict__ row, const int* __restrict__ col,
                               const float* __restrict__ pos,
                               int* __restrict__ cur,
                               int* __restrict__ rowsS, int* __restrict__ colsS,
                               float* __restrict__ d2S, int nE) {
    int e = blockIdx.x * blockDim.x + threadIdx.x;
    if (e >= nE) return;
    int r = row[e], c = col[e];
    int p = atomicAdd(&cur[r], 1);
    rowsS[p] = r;
    colsS[p] = c;
    float dx = pos[r * 3 + 0] - pos[c * 3 + 0];
    float dy = pos[r * 3 + 1] - pos[c * 3 + 1];
    float dz = pos[r * 3 + 2] - pos[c * 3 + 2];
    d2S[p] = dx * dx + dy * dy + dz * dz;
}

// ---------------- edge MLP via MFMA on sorted edges --------------------------
// launch_bounds(256,3): LDS pins 3 blocks/CU anyway; let VGPRs go to ~168 so
// gathers and B-fragment loads pipeline instead of serializing on vmcnt.
__global__ __launch_bounds__(256, 3) void edge_reg(
    const unsigned short* __restrict__ hb,
    const int* __restrict__ rowsS, const int* __restrict__ colsS,
    const float* __restrict__ d2S,
    const unsigned short* __restrict__ pb1, const float* __restrict__ b1,
    const float* __restrict__ w1last,
    const unsigned short* __restrict__ pb2, const float* __restrict__ b2,
    float* __restrict__ agg, int nE)
{
    __shared__ __align__(16) unsigned short sA[ET * 264];  // [m][k<256]
    __shared__ __align__(16) unsigned short sT[ET * 136];  // [m][k<128]
    __shared__ int   sRow[ET];
    __shared__ int   sCol[ET];
    __shared__ float sD2[ET];

    const int t = threadIdx.x;
    const int p0 = blockIdx.x * ET;

    if (t < ET) {
        int p = p0 + t;
        if (p < nE) { sRow[t] = rowsS[p]; sCol[t] = colsS[p]; sD2[t] = d2S[p]; }
        else        { sRow[t] = -1;       sCol[t] = 0;        sD2[t] = 0.f;    }
    }

    const int lane = t & 63;
    const int wv = t >> 6;
    const int wm = wv & 1, wn = wv >> 1;
    const int lm = lane & 31, lh = lane >> 5;
    const int n0 = wn * 64 + lm;

    // prefetch GEMM1 ks=0 B-fragments while indices land
    frag_u cb0, cb1, nb0, nb1;
    cb0.u = *(const ushort8*)(pb1 + (size_t)((wn * 2 + 0) * 64 + lane) * 8);
    cb1.u = *(const ushort8*)(pb1 + (size_t)((wn * 2 + 1) * 64 + lane) * 8);

    __syncthreads();

    // gather A = [h[row] | h[col]]: all 8 loads in flight, then 8 LDS writes
    ushort8 gv[8];
    int goff[8];
    #pragma unroll
    for (int i = 0; i < 8; ++i) {
        int c = t + i * 256;
        int e = c >> 5;
        int half = (c >> 4) & 1;
        int node = half ? sCol[e] : sRow[e];
        if (node < 0) node = 0;
        gv[i] = *(const ushort8*)(hb + (size_t)node * H + (c & 15) * 8);
        goff[i] = e * 264 + (c & 15) * 8 + half * 128;
    }
    #pragma unroll
    for (int i = 0; i < 8; ++i)
        *(ushort8*)(sA + goff[i]) = gv[i];
    __syncthreads();

    const float bias10 = b1[n0], bias11 = b1[n0 + 32];
    const float wl0 = w1last[n0], wl1 = w1last[n0 + 32];
    const float bias20 = b2[n0], bias21 = b2[n0 + 32];

    // GEMM1: [64,256] @ [256,128], register double-buffered B
    floatx16 acc0 = {}, acc1 = {};
    const unsigned short* A0 = sA + (wm * 32 + lm) * 264 + lh * 8;
    #pragma unroll
    for (int ks = 0; ks < 16; ++ks) {
        if (ks < 15) {
            nb0.u = *(const ushort8*)(pb1 + (size_t)(((ks + 1) * 4 + wn * 2 + 0) * 64 + lane) * 8);
            nb1.u = *(const ushort8*)(pb1 + (size_t)(((ks + 1) * 4 + wn * 2 + 1) * 64 + lane) * 8);
        }
        frag_u a;
        a.u = *(const ushort8*)(A0 + ks * 16);
        acc0 = __builtin_amdgcn_mfma_f32_32x32x16_bf16(a.b, cb0.b, acc0, 0, 0, 0);
        acc1 = __builtin_amdgcn_mfma_f32_32x32x16_bf16(a.b, cb1.b, acc1, 0, 0, 0);
        cb0 = nb0; cb1 = nb1;
    }

    // prefetch ALL GEMM2 B-fragments; they fly during epilogue-1 + barrier
    frag_u g2a[8], g2b[8];
    #pragma unroll
    for (int ks = 0; ks < 8; ++ks) {
        g2a[ks].u = *(const ushort8*)(pb2 + (size_t)((ks * 4 + wn * 2 + 0) * 64 + lane) * 8);
        g2b[ks].u = *(const ushort8*)(pb2 + (size_t)((ks * 4 + wn * 2 + 1) * 64 + lane) * 8);
    }

    // epilogue 1: bias + d2*W1last, silu -> sT
    #pragma unroll
    for (int r = 0; r < 16; ++r) {
        int m = wm * 32 + (r & 3) + 8 * (r >> 2) + 4 * lh;
        float dd = sD2[m];
        sT[m * 136 + n0]      = f2b(silu(acc0[r] + bias10 + dd * wl0));
        sT[m * 136 + n0 + 32] = f2b(silu(acc1[r] + bias11 + dd * wl1));
    }
    __syncthreads();

    // GEMM2: [64,128] @ [128,128], B already in registers
    floatx16 c0 = {}, c1 = {};
    const unsigned short* A2 = sT + (wm * 32 + lm) * 136 + lh * 8;
    #pragma unroll
    for (int ks = 0; ks < 8; ++ks) {
        frag_u a;
        a.u = *(const ushort8*)(A2 + ks * 16);
        c0 = __builtin_amdgcn_mfma_f32_32x32x16_bf16(a.b, g2a[ks].b, c0, 0, 0, 0);
        c1 = __builtin_amdgcn_mfma_f32_32x32x16_bf16(a.b, g2b[ks].b, c1, 0, 0, 0);
    }

    // epilogue 2: silu + register run-compaction over 4 consecutive sorted edges
    #pragma unroll
    for (int g = 0; g < 4; ++g) {
        const int m0 = wm * 32 + 4 * lh + 8 * g;
        int prow = sRow[m0];
        float s0 = silu(c0[g * 4] + bias20);
        float s1 = silu(c1[g * 4] + bias21);
        #pragma unroll
        for (int k = 1; k < 4; ++k) {
            int rw = sRow[m0 + k];
            float u0 = silu(c0[g * 4 + k] + bias20);
            float u1 = silu(c1[g * 4 + k] + bias21);
            if (rw == prow) {
                s0 += u0; s1 += u1;
            } else {
                if (prow >= 0) {
                    atomicAdd(&agg[(size_t)prow * H + n0],      s0);
                    atomicAdd(&agg[(size_t)prow * H + n0 + 32], s1);
                }
                prow = rw; s0 = u0; s1 = u1;
            }
        }
        if (prow >= 0) {
            atomicAdd(&agg[(size_t)prow * H + n0],      s0);
            atomicAdd(&agg[(size_t)prow * H + n0 + 32], s1);
        }
    }
}

// ---------------- node MLP via MFMA (same ILP treatment) ----------------
__global__ __launch_bounds__(256, 3) void node_mfma(
    const unsigned short* __restrict__ hb,
    const float* __restrict__ aggf,
    const unsigned short* __restrict__ pn1, const float* __restrict__ b1,
    const unsigned short* __restrict__ pn2, const float* __restrict__ b2,
    float* __restrict__ hnew, int nN)
{
    __shared__ __align__(16) unsigned short sA[ET * 264];
    __shared__ __align__(16) unsigned short sT[ET * 136];

    const int t = threadIdx.x;
    const int i0 = blockIdx.x * ET;

    const int lane = t & 63;
    const int wv = t >> 6;
    const int wm = wv & 1, wn = wv >> 1;
    const int lm = lane & 31, lh = lane >> 5;
    const int n0 = wn * 64 + lm;

    frag_u cb0, cb1, nb0, nb1;
    cb0.u = *(const ushort8*)(pn1 + (size_t)((wn * 2 + 0) * 64 + lane) * 8);
    cb1.u = *(const ushort8*)(pn1 + (size_t)((wn * 2 + 1) * 64 + lane) * 8);

    #pragma unroll
    for (int c = t; c < ET * 32; c += 256) {
        int e = c >> 5;
        int node = i0 + e; if (node >= nN) node = nN - 1;
        int f0 = (c & 31) * 8;
        ushort8 v;
        if (f0 < H) {
            v = *(const ushort8*)(hb + (size_t)node * H + f0);
        } else {
            const float* src = aggf + (size_t)node * H + (f0 - H);
            #pragma unroll
            for (int j = 0; j < 8; ++j) v[j] = f2b(src[j]);
        }
        *(ushort8*)(sA + e * 264 + (c & 31) * 8) = v;
    }
    __syncthreads();

    floatx16 acc0 = {}, acc1 = {};
    const unsigned short* A0 = sA + (wm * 32 + lm) * 264 + lh * 8;
    #pragma unroll
    for (int ks = 0; ks < 16; ++ks) {
        if (ks < 15) {
            nb0.u = *(const ushort8*)(pn1 + (size_t)(((ks + 1) * 4 + wn * 2 + 0) * 64 + lane) * 8);
            nb1.u = *(const ushort8*)(pn1 + (size_t)(((ks + 1) * 4 + wn * 2 + 1) * 64 + lane) * 8);
        }
        frag_u a;
        a.u = *(const ushort8*)(A0 + ks * 16);
        acc0 = __builtin_amdgcn_mfma_f32_32x32x16_bf16(a.b, cb0.b, acc0, 0, 0, 0);
        acc1 = __builtin_amdgcn_mfma_f32_32x32x16_bf16(a.b, cb1.b, acc1, 0, 0, 0);
        cb0 = nb0; cb1 = nb1;
    }

    frag_u g2a[8], g2b[8];
    #pragma unroll
    for (int ks = 0; ks < 8; ++ks) {
        g2a[ks].u = *(const ushort8*)(pn2 + (size_t)((ks * 4 + wn * 2 + 0) * 64 + lane) * 8);
        g2b[ks].u = *(const ushort8*)(pn2 + (size_t)((ks * 4 + wn * 2 + 1) * 64 + lane) * 8);
    }

    {
        float bias0 = b1[n0], bias1 = b1[n0 + 32];
        #pragma unroll
        for (int r = 0; r < 16; ++r) {
            int m = wm * 32 + (r & 3) + 8 * (r >> 2) + 4 * lh;
            sT[m * 136 + n0]      = f2b(silu(acc0[r] + bias0));
            sT[m * 136 + n0 + 32] = f2b(silu(acc1[r] + bias1));
        }
    }
    __syncthreads();

    floatx16 c0 = {}, c1 = {};
    const unsigned short* A2 = sT + (wm * 32 + lm) * 136 + lh * 8;
    #pragma unroll
    for (int ks = 0; ks < 8; ++ks) {
        frag_u a;
        a.u = *(const ushort8*)(A2 + ks * 16);
        c0 = __builtin_amdgcn_mfma_f32_32x32x16_bf16(a.b, g2a[ks].b, c0, 0, 0, 0);
        c1 = __builtin_amdgcn_mfma_f32_32x32x16_bf16(a.b, g2b[ks].b, c1, 0, 0, 0);
    }
    {
        float bias0 = b2[n0], bias1 = b2[n0 + 32];
        #pragma unroll
        for (int r = 0; r < 16; ++r) {
            int m = wm * 32 + (r & 3) + 8 * (r >> 2) + 4 * lh;
            int node = i0 + m;
            if (node < nN) {
                float* dst = hnew + (size_t)node * H;
                dst[n0]      = c0[r] + bias0;
                dst[n0 + 32] = c1[r] + bias1;
            }
        }
    }
}

// residual + layernorm; writes fp32 h and bf16 mirror
__global__ __launch_bounds__(256) void ln_kernel(
    float* __restrict__ h, unsigned short* __restrict__ hb,
    const float* __restrict__ hnew,
    const float* __restrict__ G, const float* __restrict__ B, int nN)
{
    __shared__ float rs[4], rq[4];
    int t = threadIdx.x;
    int local = t >> 7, j = t & 127;
    int i = blockIdx.x * 2 + local;
    float v = 0.f;
    if (i < nN) v = h[(size_t)i * H + j] + hnew[(size_t)i * H + j];
    float s = v, q = v * v;
    #pragma unroll
    for (int off = 32; off > 0; off >>= 1) {
        s += __shfl_down(s, off);
        q += __shfl_down(q, off);
    }
    int w = t >> 6;
    if ((t & 63) == 0) { rs[w] = s; rq[w] = q; }
    __syncthreads();
    int w0 = local * 2;
    float S = rs[w0] + rs[w0 + 1], Q = rq[w0] + rq[w0 + 1];
    float mu = S * (1.f / H);
    float var = Q * (1.f / H) - mu * mu;
    float y = (v - mu) * rsqrtf(var + LN_EPS) * G[j] + B[j];
    if (i < nN) {
        h[(size_t)i * H + j] = y;
        hb[(size_t)i * H + j] = f2b(y);
    }
}

__global__ void cast_kernel(const float* __restrict__ h, void* __restrict__ out,
                            int n, const int* __restrict__ flag) {
    int idx = blockIdx.x * blockDim.x + threadIdx.x;
    if (idx >= n) return;
    if (*flag) ((float*)out)[idx] = h[idx];
    else       ((hipbf16*)out)[idx] = __float2bfloat16(h[idx]);
}

extern "C" void kernel_launch(void* const* d_in, const int* in_sizes, int n_in,
                              void* d_out, int out_size, void* d_ws, size_t ws_size,
                              hipStream_t stream)
{
    const int* z  = (const int*)d_in[0];
    const int* ei = (const int*)d_in[2];

    const int nN = in_sizes[0];
    const int nE = in_sizes[2] / 2;
    const int* row = ei;
    const int* col = ei + nE;

    // ---- workspace layout (~77 MB total, proven safe) ----
    float* ws   = (float*)d_ws;
    int*   flag = (int*)ws;
    float* h    = ws + 64;
    unsigned short* hb = (unsigned short*)(h + (size_t)nN * H);
    float* agg  = (float*)(hb + (size_t)nN * H);
    float* conv = agg + (size_t)nN * H;

    const int n_pos = in_sizes[1];
    const int n_emb = in_sizes[3];
    const int n_ew1 = in_sizes[4], n_eb1 = in_sizes[5];
    const int n_ew2 = in_sizes[6], n_eb2 = in_sizes[7];
    const int n_nw1 = in_sizes[8], n_nb1 = in_sizes[9];
    const int n_nw2 = in_sizes[10], n_nb2 = in_sizes[11];
    const int n_lng = in_sizes[12], n_lnb = in_sizes[13];

    float* pos = conv;
    float* emb = pos + n_pos;
    float* ew1 = emb + n_emb;
    float* eb1 = ew1 + n_ew1;
    float* ew2 = eb1 + n_eb1;
    float* eb2 = ew2 + n_ew2;
    float* nw1 = eb2 + n_eb2;
    float* nb1 = nw1 + n_nw1;
    float* nw2 = nb1 + n_nb1;
    float* nb2 = nw2 + n_nw2;
    float* lng = nb2 + n_nb2;
    float* lnb = lng + n_lng;
    float* conv_end = lnb + n_lnb;

    unsigned short* pb1 = (unsigned short*)conv_end;          // 4 x 32768
    unsigned short* pb2 = pb1 + 4 * 32768;                    // 4 x 16384
    unsigned short* pn1 = pb2 + 4 * 16384;                    // 4 x 32768
    unsigned short* pn2 = pn1 + 4 * 32768;                    // 4 x 16384

    int* cnt   = (int*)(pn2 + 4 * 16384);
    int* rptr  = cnt + nN;
    int* cur   = rptr + nN + 1;
    int* rowsS = cur + nN;
    int* colsS = rowsS + nE;
    float* d2S = (float*)(colsS + nE);

    detect_kernel<<<1, 64, 0, stream>>>((const unsigned short*)d_in[4], 4096, flag);

    struct { const void* src; float* dst; int n; } cv[12] = {
        {d_in[1],  pos, n_pos}, {d_in[3],  emb, n_emb},
        {d_in[4],  ew1, n_ew1}, {d_in[5],  eb1, n_eb1},
        {d_in[6],  ew2, n_ew2}, {d_in[7],  eb2, n_eb2},
        {d_in[8],  nw1, n_nw1}, {d_in[9],  nb1, n_nb1},
        {d_in[10], nw2, n_nw2}, {d_in[11], nb2, n_nb2},
        {d_in[12], lng, n_lng}, {d_in[13], lnb, n_lnb},
    };
    for (int i = 0; i < 12; ++i)
        conv_kernel<<<(cv[i].n + 255) / 256, 256, 0, stream>>>(cv[i].src, cv[i].dst, cv[i].n, flag);

    for (int l = 0; l < NLAYERS; ++l) {
        pack_kernel<<<128, 256, 0, stream>>>(ew1 + (size_t)l * 257 * H, pb1 + l * 32768, 16);
        pack_kernel<<<64,  256, 0, stream>>>(ew2 + (size_t)l * H * H,   pb2 + l * 16384, 8);
        pack_kernel<<<128, 256, 0, stream>>>(nw1 + (size_t)l * 2 * H * H, pn1 + l * 32768, 16);
        pack_kernel<<<64,  256, 0, stream>>>(nw2 + (size_t)l * H * H,   pn2 + l * 16384, 8);
    }

    // CSR-order edges (counting sort by destination row)
    hipMemsetAsync(cnt, 0, (size_t)nN * sizeof(int), stream);
    hist_kernel<<<(nE + 255) / 256, 256, 0, stream>>>(row, cnt, nE);
    scan_kernel<<<1, 1024, 0, stream>>>(cnt, rptr, cur, nN);
    scatter_kernel<<<(nE + 255) / 256, 256, 0, stream>>>(row, col, pos, cur, rowsS, colsS, d2S, nE);

    embed_kernel<<<(nN * H + 255) / 256, 256, 0, stream>>>(z, emb, h, hb, nN);

    const int nTiles = (nE + ET - 1) / ET;
    for (int l = 0; l < NLAYERS; ++l) {
        hipMemsetAsync(agg, 0, (size_t)nN * H * sizeof(float), stream);
        edge_reg<<<nTiles, 256, 0, stream>>>(
            hb, rowsS, colsS, d2S,
            pb1 + l * 32768, eb1 + (size_t)l * H,
            ew1 + (size_t)l * 257 * H + 256 * H,
            pb2 + l * 16384, eb2 + (size_t)l * H,
            agg, nE);
        node_mfma<<<(nN + ET - 1) / ET, 256, 0, stream>>>(
            hb, agg,
            pn1 + l * 32768, nb1 + (size_t)l * H,
            pn2 + l * 16384, nb2 + (size_t)l * H,
            agg /* hnew, overwritten in place */, nN);
        ln_kernel<<<(nN + 1) / 2, 256, 0, stream>>>(
            h, hb, agg, lng + (size_t)l * H, lnb + (size_t)l * H, nN);
    }
    cast_kernel<<<(nN * H + 255) / 256, 256, 0, stream>>>(h, d_out, nN * H, flag);
}

// Round 9
// 1455.315 us; speedup vs baseline: 3.5631x; 1.1070x over previous
//
#include <hip/hip_runtime.h>
#include <hip/hip_bf16.h>

typedef __hip_bfloat16 hipbf16;

#define H 128
#define NLAYERS 4
#define LN_EPS 1e-5f
#define ET 64           // edges/nodes per MFMA tile

typedef __bf16 bf16x8 __attribute__((ext_vector_type(8)));
typedef unsigned short ushort8 __attribute__((ext_vector_type(8)));
typedef float floatx16 __attribute__((ext_vector_type(16)));

union frag_u { ushort8 u; bf16x8 b; };

// fast silu: v_exp + v_rcp + 2 mul/add (vs IEEE div sequence ~15 inst).
// rcp is ~1ulp fp32 -> far below bf16 output precision.
__device__ __forceinline__ float silu(float x) {
    return x * __builtin_amdgcn_rcpf(1.f + __expf(-x));
}
__device__ __forceinline__ float b2f_bits(unsigned short u) { return __uint_as_float(((unsigned)u) << 16); }
__device__ __forceinline__ unsigned short f2b(float f) {
    unsigned u = __float_as_uint(f);
    unsigned r = ((u >> 16) & 1u) + 0x7fffu;
    return (unsigned short)((u + r) >> 16);
}

// ---------------- dtype detection (wire fp32 vs bf16) ----------------
__global__ void detect_kernel(const unsigned short* __restrict__ p, int nHalf,
                              int* __restrict__ flag) {
    int t = threadIdx.x;
    int bad = 0;
    for (int i = t; i < nHalf; i += 64) {
        unsigned short u = p[i];
        int e = (u >> 7) & 0xFF;
        if (e >= 0x8E) bad = 1;
    }
    unsigned long long m = __ballot(bad != 0);
    if (t == 0) *flag = (m != 0ULL) ? 1 : 0;   // 1 => fp32 wire
}

__global__ void conv_kernel(const void* __restrict__ src, float* __restrict__ dst,
                            int n, const int* __restrict__ flag) {
    int i = blockIdx.x * blockDim.x + threadIdx.x;
    if (i >= n) return;
    if (*flag) dst[i] = ((const float*)src)[i];
    else       dst[i] = b2f_bits(((const unsigned short*)src)[i]);
}

// Pack W[K x 128] (fp32) into MFMA B-fragment order
__global__ void pack_kernel(const float* __restrict__ W, unsigned short* __restrict__ blob,
                            int ksteps) {
    int idx = blockIdx.x * 256 + threadIdx.x;
    if (idx >= ksteps * 2048) return;
    int j  = idx & 7;
    int L  = (idx >> 3) & 63;
    int nt = (idx >> 9) & 3;
    int ks = idx >> 11;
    int k = ks * 16 + (L >> 5) * 8 + j;
    int n = nt * 32 + (L & 31);
    blob[idx] = f2b(W[k * H + n]);
}

__global__ void embed_kernel(const int* __restrict__ z, const float* __restrict__ emb,
                             float* __restrict__ h, unsigned short* __restrict__ hb, int n) {
    int idx = blockIdx.x * blockDim.x + threadIdx.x;
    if (idx >= n * H) return;
    int i = idx >> 7, j = idx & 127;
    float v = emb[z[i] * H + j];
    h[idx] = v;
    hb[idx] = f2b(v);
}

// ---------------- CSR build (counting sort by destination row) ----------------
__global__ void hist_kernel(const int* __restrict__ row, int* __restrict__ cnt, int nE) {
    int i = blockIdx.x * blockDim.x + threadIdx.x;
    if (i < nE) atomicAdd(&cnt[row[i]], 1);
}

__global__ __launch_bounds__(1024) void scan_kernel(const int* __restrict__ cnt,
                                                    int* __restrict__ rptr,
                                                    int* __restrict__ cur, int nN) {
    __shared__ int wsum[17];
    __shared__ int s_carry;
    int t = threadIdx.x;
    if (t == 0) s_carry = 0;
    __syncthreads();
    for (int base = 0; base < nN; base += 1024) {
        int i = base + t;
        int v = (i < nN) ? cnt[i] : 0;
        int x = v;
        #pragma unroll
        for (int off = 1; off < 64; off <<= 1) {
            int y = __shfl_up(x, off);
            if ((t & 63) >= off) x += y;
        }
        if ((t & 63) == 63) wsum[t >> 6] = x;
        __syncthreads();
        if (t == 0) {
            int s = 0;
            #pragma unroll
            for (int w = 0; w < 16; ++w) { int tmp = wsum[w]; wsum[w] = s; s += tmp; }
            wsum[16] = s;
        }
        __syncthreads();
        int cin = s_carry;
        int excl = cin + wsum[t >> 6] + (x - v);
        if (i < nN) { rptr[i] = excl; cur[i] = excl; }
        __syncthreads();
        if (t == 0) s_carry = cin + wsum[16];
        __syncthreads();
    }
    if (t == 0) rptr[nN] = s_carry;
}

__global__ void scatter_kernel(const int* __restrict__ row, const int* __restrict__ col,
                               const float* __restrict__ pos,
                               int* __restrict__ cur,
                               int* __restrict__ rowsS, int* __restrict__ colsS,
                               float* __restrict__ d2S, int nE) {
    int e = blockIdx.x * blockDim.x + threadIdx.x;
    if (e >= nE) return;
    int r = row[e], c = col[e];
    int p = atomicAdd(&cur[r], 1);
    rowsS[p] = r;
    colsS[p] = c;
    float dx = pos[r * 3 + 0] - pos[c * 3 + 0];
    float dy = pos[r * 3 + 1] - pos[c * 3 + 1];
    float dz = pos[r * 3 + 2] - pos[c * 3 + 2];
    d2S[p] = dx * dx + dy * dy + dz * dz;
}

// ---------------- edge MLP via MFMA on sorted edges --------------------------
// sT aliased onto sA (extra barrier after GEMM1) -> LDS ~35KB -> 4 blocks/CU.
__global__ __launch_bounds__(256) void edge_reg(
    const unsigned short* __restrict__ hb,
    const int* __restrict__ rowsS, const int* __restrict__ colsS,
    const float* __restrict__ d2S,
    const unsigned short* __restrict__ pb1, const float* __restrict__ b1,
    const float* __restrict__ w1last,
    const unsigned short* __restrict__ pb2, const float* __restrict__ b2,
    float* __restrict__ agg, int nE)
{
    __shared__ __align__(16) unsigned short sA[ET * 264];  // GEMM1 A; sT aliased
    __shared__ int   sRow[ET];
    __shared__ int   sCol[ET];
    __shared__ float sD2[ET];

    const int t = threadIdx.x;
    const int p0 = blockIdx.x * ET;

    if (t < ET) {
        int p = p0 + t;
        if (p < nE) { sRow[t] = rowsS[p]; sCol[t] = colsS[p]; sD2[t] = d2S[p]; }
        else        { sRow[t] = -1;       sCol[t] = 0;        sD2[t] = 0.f;    }
    }
    __syncthreads();

    // gather A = [h[row] | h[col]] in bf16
    #pragma unroll
    for (int i = 0; i < 8; ++i) {
        int c = t + i * 256;
        int e = c >> 5;
        int half = (c >> 4) & 1;
        int node = half ? sCol[e] : sRow[e];
        if (node < 0) node = 0;
        ushort8 v = *(const ushort8*)(hb + (size_t)node * H + (c & 15) * 8);
        *(ushort8*)(sA + e * 264 + (c & 15) * 8 + half * 128) = v;
    }
    __syncthreads();

    const int lane = t & 63;
    const int wv = t >> 6;
    const int wm = wv & 1, wn = wv >> 1;
    const int lm = lane & 31, lh = lane >> 5;
    const int n0 = wn * 64 + lm;

    const float bias10 = b1[n0], bias11 = b1[n0 + 32];
    const float wl0 = w1last[n0], wl1 = w1last[n0 + 32];
    const float bias20 = b2[n0], bias21 = b2[n0 + 32];

    // GEMM1: [64,256] @ [256,128]
    floatx16 acc0 = {}, acc1 = {};
    const unsigned short* A0 = sA + (wm * 32 + lm) * 264 + lh * 8;
    #pragma unroll
    for (int ks = 0; ks < 16; ++ks) {
        frag_u a, fb0, fb1;
        a.u   = *(const ushort8*)(A0 + ks * 16);
        fb0.u = *(const ushort8*)(pb1 + (size_t)((ks * 4 + wn * 2 + 0) * 64 + lane) * 8);
        fb1.u = *(const ushort8*)(pb1 + (size_t)((ks * 4 + wn * 2 + 1) * 64 + lane) * 8);
        acc0 = __builtin_amdgcn_mfma_f32_32x32x16_bf16(a.b, fb0.b, acc0, 0, 0, 0);
        acc1 = __builtin_amdgcn_mfma_f32_32x32x16_bf16(a.b, fb1.b, acc1, 0, 0, 0);
    }
    __syncthreads();   // all sA reads complete before sT (aliased) is written

    // epilogue 1: bias + d2*W1last, silu -> sT
    unsigned short* sT = sA;   // [m][k<128], stride 136
    #pragma unroll
    for (int r = 0; r < 16; ++r) {
        int m = wm * 32 + (r & 3) + 8 * (r >> 2) + 4 * lh;
        float dd = sD2[m];
        sT[m * 136 + n0]      = f2b(silu(acc0[r] + bias10 + dd * wl0));
        sT[m * 136 + n0 + 32] = f2b(silu(acc1[r] + bias11 + dd * wl1));
    }
    __syncthreads();

    // GEMM2: [64,128] @ [128,128]
    floatx16 c0 = {}, c1 = {};
    const unsigned short* A2 = sT + (wm * 32 + lm) * 136 + lh * 8;
    #pragma unroll
    for (int ks = 0; ks < 8; ++ks) {
        frag_u a, fb0, fb1;
        a.u   = *(const ushort8*)(A2 + ks * 16);
        fb0.u = *(const ushort8*)(pb2 + (size_t)((ks * 4 + wn * 2 + 0) * 64 + lane) * 8);
        fb1.u = *(const ushort8*)(pb2 + (size_t)((ks * 4 + wn * 2 + 1) * 64 + lane) * 8);
        c0 = __builtin_amdgcn_mfma_f32_32x32x16_bf16(a.b, fb0.b, c0, 0, 0, 0);
        c1 = __builtin_amdgcn_mfma_f32_32x32x16_bf16(a.b, fb1.b, c1, 0, 0, 0);
    }

    // epilogue 2: silu + register run-compaction over 4 consecutive sorted edges
    #pragma unroll
    for (int g = 0; g < 4; ++g) {
        const int m0 = wm * 32 + 4 * lh + 8 * g;
        int prow = sRow[m0];
        float s0 = silu(c0[g * 4] + bias20);
        float s1 = silu(c1[g * 4] + bias21);
        #pragma unroll
        for (int k = 1; k < 4; ++k) {
            int rw = sRow[m0 + k];
            float u0 = silu(c0[g * 4 + k] + bias20);
            float u1 = silu(c1[g * 4 + k] + bias21);
            if (rw == prow) {
                s0 += u0; s1 += u1;
            } else {
                if (prow >= 0) {
                    atomicAdd(&agg[(size_t)prow * H + n0],      s0);
                    atomicAdd(&agg[(size_t)prow * H + n0 + 32], s1);
                }
                prow = rw; s0 = u0; s1 = u1;
            }
        }
        if (prow >= 0) {
            atomicAdd(&agg[(size_t)prow * H + n0],      s0);
            atomicAdd(&agg[(size_t)prow * H + n0 + 32], s1);
        }
    }
}

// ---------------- node MLP via MFMA (sT aliased too) ----------------
__global__ __launch_bounds__(256) void node_mfma(
    const unsigned short* __restrict__ hb,
    const float* __restrict__ aggf,
    const unsigned short* __restrict__ pn1, const float* __restrict__ b1,
    const unsigned short* __restrict__ pn2, const float* __restrict__ b2,
    float* __restrict__ hnew, int nN)
{
    __shared__ __align__(16) unsigned short sA[ET * 264];

    const int t = threadIdx.x;
    const int i0 = blockIdx.x * ET;

    #pragma unroll
    for (int c = t; c < ET * 32; c += 256) {
        int e = c >> 5;
        int node = i0 + e; if (node >= nN) node = nN - 1;
        int f0 = (c & 31) * 8;
        ushort8 v;
        if (f0 < H) {
            v = *(const ushort8*)(hb + (size_t)node * H + f0);
        } else {
            const float* src = aggf + (size_t)node * H + (f0 - H);
            #pragma unroll
            for (int j = 0; j < 8; ++j) v[j] = f2b(src[j]);
        }
        *(ushort8*)(sA + e * 264 + (c & 31) * 8) = v;
    }
    __syncthreads();

    const int lane = t & 63;
    const int wv = t >> 6;
    const int wm = wv & 1, wn = wv >> 1;
    const int lm = lane & 31, lh = lane >> 5;
    const int n0 = wn * 64 + lm;

    floatx16 acc0 = {}, acc1 = {};
    const unsigned short* A0 = sA + (wm * 32 + lm) * 264 + lh * 8;
    #pragma unroll
    for (int ks = 0; ks < 16; ++ks) {
        frag_u a, fb0, fb1;
        a.u   = *(const ushort8*)(A0 + ks * 16);
        fb0.u = *(const ushort8*)(pn1 + (size_t)((ks * 4 + wn * 2 + 0) * 64 + lane) * 8);
        fb1.u = *(const ushort8*)(pn1 + (size_t)((ks * 4 + wn * 2 + 1) * 64 + lane) * 8);
        acc0 = __builtin_amdgcn_mfma_f32_32x32x16_bf16(a.b, fb0.b, acc0, 0, 0, 0);
        acc1 = __builtin_amdgcn_mfma_f32_32x32x16_bf16(a.b, fb1.b, acc1, 0, 0, 0);
    }
    __syncthreads();   // sA reads done before sT (aliased) written

    unsigned short* sT = sA;
    {
        float bias0 = b1[n0], bias1 = b1[n0 + 32];
        #pragma unroll
        for (int r = 0; r < 16; ++r) {
            int m = wm * 32 + (r & 3) + 8 * (r >> 2) + 4 * lh;
            sT[m * 136 + n0]      = f2b(silu(acc0[r] + bias0));
            sT[m * 136 + n0 + 32] = f2b(silu(acc1[r] + bias1));
        }
    }
    __syncthreads();

    floatx16 c0 = {}, c1 = {};
    const unsigned short* A2 = sT + (wm * 32 + lm) * 136 + lh * 8;
    #pragma unroll
    for (int ks = 0; ks < 8; ++ks) {
        frag_u a, fb0, fb1;
        a.u   = *(const ushort8*)(A2 + ks * 16);
        fb0.u = *(const ushort8*)(pn2 + (size_t)((ks * 4 + wn * 2 + 0) * 64 + lane) * 8);
        fb1.u = *(const ushort8*)(pn2 + (size_t)((ks * 4 + wn * 2 + 1) * 64 + lane) * 8);
        c0 = __builtin_amdgcn_mfma_f32_32x32x16_bf16(a.b, fb0.b, c0, 0, 0, 0);
        c1 = __builtin_amdgcn_mfma_f32_32x32x16_bf16(a.b, fb1.b, c1, 0, 0, 0);
    }
    {
        float bias0 = b2[n0], bias1 = b2[n0 + 32];
        #pragma unroll
        for (int r = 0; r < 16; ++r) {
            int m = wm * 32 + (r & 3) + 8 * (r >> 2) + 4 * lh;
            int node = i0 + m;
            if (node < nN) {
                float* dst = hnew + (size_t)node * H;
                dst[n0]      = c0[r] + bias0;
                dst[n0 + 32] = c1[r] + bias1;
            }
        }
    }
}

// residual + layernorm; writes fp32 h and bf16 mirror
__global__ __launch_bounds__(256) void ln_kernel(
    float* __restrict__ h, unsigned short* __restrict__ hb,
    const float* __restrict__ hnew,
    const float* __restrict__ G, const float* __restrict__ B, int nN)
{
    __shared__ float rs[4], rq[4];
    int t = threadIdx.x;
    int local = t >> 7, j = t & 127;
    int i = blockIdx.x * 2 + local;
    float v = 0.f;
    if (i < nN) v = h[(size_t)i * H + j] + hnew[(size_t)i * H + j];
    float s = v, q = v * v;
    #pragma unroll
    for (int off = 32; off > 0; off >>= 1) {
        s += __shfl_down(s, off);
        q += __shfl_down(q, off);
    }
    int w = t >> 6;
    if ((t & 63) == 0) { rs[w] = s; rq[w] = q; }
    __syncthreads();
    int w0 = local * 2;
    float S = rs[w0] + rs[w0 + 1], Q = rq[w0] + rq[w0 + 1];
    float mu = S * (1.f / H);
    float var = Q * (1.f / H) - mu * mu;
    float y = (v - mu) * rsqrtf(var + LN_EPS) * G[j] + B[j];
    if (i < nN) {
        h[(size_t)i * H + j] = y;
        hb[(size_t)i * H + j] = f2b(y);
    }
}

__global__ void cast_kernel(const float* __restrict__ h, void* __restrict__ out,
                            int n, const int* __restrict__ flag) {
    int idx = blockIdx.x * blockDim.x + threadIdx.x;
    if (idx >= n) return;
    if (*flag) ((float*)out)[idx] = h[idx];
    else       ((hipbf16*)out)[idx] = __float2bfloat16(h[idx]);
}

extern "C" void kernel_launch(void* const* d_in, const int* in_sizes, int n_in,
                              void* d_out, int out_size, void* d_ws, size_t ws_size,
                              hipStream_t stream)
{
    const int* z  = (const int*)d_in[0];
    const int* ei = (const int*)d_in[2];

    const int nN = in_sizes[0];
    const int nE = in_sizes[2] / 2;
    const int* row = ei;
    const int* col = ei + nE;

    // ---- workspace layout (~77 MB total, proven safe) ----
    float* ws   = (float*)d_ws;
    int*   flag = (int*)ws;
    float* h    = ws + 64;
    unsigned short* hb = (unsigned short*)(h + (size_t)nN * H);
    float* agg  = (float*)(hb + (size_t)nN * H);
    float* conv = agg + (size_t)nN * H;

    const int n_pos = in_sizes[1];
    const int n_emb = in_sizes[3];
    const int n_ew1 = in_sizes[4], n_eb1 = in_sizes[5];
    const int n_ew2 = in_sizes[6], n_eb2 = in_sizes[7];
    const int n_nw1 = in_sizes[8], n_nb1 = in_sizes[9];
    const int n_nw2 = in_sizes[10], n_nb2 = in_sizes[11];
    const int n_lng = in_sizes[12], n_lnb = in_sizes[13];

    float* pos = conv;
    float* emb = pos + n_pos;
    float* ew1 = emb + n_emb;
    float* eb1 = ew1 + n_ew1;
    float* ew2 = eb1 + n_eb1;
    float* eb2 = ew2 + n_ew2;
    float* nw1 = eb2 + n_eb2;
    float* nb1 = nw1 + n_nw1;
    float* nw2 = nb1 + n_nb1;
    float* nb2 = nw2 + n_nw2;
    float* lng = nb2 + n_nb2;
    float* lnb = lng + n_lng;
    float* conv_end = lnb + n_lnb;

    unsigned short* pb1 = (unsigned short*)conv_end;          // 4 x 32768
    unsigned short* pb2 = pb1 + 4 * 32768;                    // 4 x 16384
    unsigned short* pn1 = pb2 + 4 * 16384;                    // 4 x 32768
    unsigned short* pn2 = pn1 + 4 * 32768;                    // 4 x 16384

    int* cnt   = (int*)(pn2 + 4 * 16384);
    int* rptr  = cnt + nN;
    int* cur   = rptr + nN + 1;
    int* rowsS = cur + nN;
    int* colsS = rowsS + nE;
    float* d2S = (float*)(colsS + nE);

    detect_kernel<<<1, 64, 0, stream>>>((const unsigned short*)d_in[4], 4096, flag);

    struct { const void* src; float* dst; int n; } cv[12] = {
        {d_in[1],  pos, n_pos}, {d_in[3],  emb, n_emb},
        {d_in[4],  ew1, n_ew1}, {d_in[5],  eb1, n_eb1},
        {d_in[6],  ew2, n_ew2}, {d_in[7],  eb2, n_eb2},
        {d_in[8],  nw1, n_nw1}, {d_in[9],  nb1, n_nb1},
        {d_in[10], nw2, n_nw2}, {d_in[11], nb2, n_nb2},
        {d_in[12], lng, n_lng}, {d_in[13], lnb, n_lnb},
    };
    for (int i = 0; i < 12; ++i)
        conv_kernel<<<(cv[i].n + 255) / 256, 256, 0, stream>>>(cv[i].src, cv[i].dst, cv[i].n, flag);

    for (int l = 0; l < NLAYERS; ++l) {
        pack_kernel<<<128, 256, 0, stream>>>(ew1 + (size_t)l * 257 * H, pb1 + l * 32768, 16);
        pack_kernel<<<64,  256, 0, stream>>>(ew2 + (size_t)l * H * H,   pb2 + l * 16384, 8);
        pack_kernel<<<128, 256, 0, stream>>>(nw1 + (size_t)l * 2 * H * H, pn1 + l * 32768, 16);
        pack_kernel<<<64,  256, 0, stream>>>(nw2 + (size_t)l * H * H,   pn2 + l * 16384, 8);
    }

    // CSR-order edges (counting sort by destination row)
    hipMemsetAsync(cnt, 0, (size_t)nN * sizeof(int), stream);
    hist_kernel<<<(nE + 255) / 256, 256, 0, stream>>>(row, cnt, nE);
    scan_kernel<<<1, 1024, 0, stream>>>(cnt, rptr, cur, nN);
    scatter_kernel<<<(nE + 255) / 256, 256, 0, stream>>>(row, col, pos, cur, rowsS, colsS, d2S, nE);

    embed_kernel<<<(nN * H + 255) / 256, 256, 0, stream>>>(z, emb, h, hb, nN);

    const int nTiles = (nE + ET - 1) / ET;
    for (int l = 0; l < NLAYERS; ++l) {
        hipMemsetAsync(agg, 0, (size_t)nN * H * sizeof(float), stream);
        edge_reg<<<nTiles, 256, 0, stream>>>(
            hb, rowsS, colsS, d2S,
            pb1 + l * 32768, eb1 + (size_t)l * H,
            ew1 + (size_t)l * 257 * H + 256 * H,
            pb2 + l * 16384, eb2 + (size_t)l * H,
            agg, nE);
        node_mfma<<<(nN + ET - 1) / ET, 256, 0, stream>>>(
            hb, agg,
            pn1 + l * 32768, nb1 + (size_t)l * H,
            pn2 + l * 16384, nb2 + (size_t)l * H,
            agg /* hnew, overwritten in place */, nN);
        ln_kernel<<<(nN + 1) / 2, 256, 0, stream>>>(
            h, hb, agg, lng + (size_t)l * H, lnb + (size_t)l * H, nN);
    }
    cast_kernel<<<(nN * H + 255) / 256, 256, 0, stream>>>(h, d_out, nN * H, flag);
}